// Round 2
// baseline (12761.630 us; speedup 1.0000x reference)
//
#include <hip/hip_runtime.h>
#include <hip/hip_bf16.h>
#include <hip/hip_cooperative_groups.h>

namespace cg = cooperative_groups;

#define BB 512     // batch
#define TT 96      // encoder steps
#define PP 96      // decoder steps
#define EE 321     // input features
#define CC 321     // output channels
#define HH 512     // hidden
#define G4 2048    // 4*H
#define EPAD 352   // 321 padded to 32
#define NFC 384    // fc N pad (64-multiple)

// double-buffered LDS staging: per buffer Xh[128][32] Xl[128][32] Wh[64][32] Wl[64][32] (u16)
#define BUF_SZ 24576
#define XH_OFF 0
#define XL_OFF 8192
#define WH_OFF 16384
#define WL_OFF 20480
#define LSTM_SMEM 49152  // 2 buffers; sG (34816 B) aliases after final barrier

typedef unsigned short u16;
typedef __attribute__((ext_vector_type(8))) short bf16x8;
typedef __attribute__((ext_vector_type(16))) float floatx16;

__device__ __forceinline__ void splitf(float v, u16& h, u16& l){
  __hip_bfloat16 bh = __float2bfloat16(v);
  h = *reinterpret_cast<u16*>(&bh);
  float r = v - __bfloat162float(bh);
  __hip_bfloat16 bl = __float2bfloat16(r);
  l = *reinterpret_cast<u16*>(&bl);
}

// async global->LDS, 16B per lane; LDS dest = wave-uniform base + lane*16 (linear).
__device__ __forceinline__ void gload16(const void* g, void* l){
  __builtin_amdgcn_global_load_lds((const __attribute__((address_space(1))) void*)g,
                                   (__attribute__((address_space(3))) void*)l, 16, 0, 0);
}

// ---------- prep: split fp32 [rows][cols] -> bf16 hi/lo [rowspad][colspad] ----------
__global__ void cvt_split(const float* __restrict__ src, u16* __restrict__ hi, u16* __restrict__ lo,
                          int rows, int cols, int rowspad, int colspad){
  int total = rowspad * colspad;
  for (int idx = blockIdx.x * blockDim.x + threadIdx.x; idx < total; idx += gridDim.x * blockDim.x){
    int r = idx / colspad, cc = idx - r * colspad;
    float v = (r < rows && cc < cols) ? src[(size_t)r * cols + cc] : 0.f;
    u16 h, l; splitf(v, h, l);
    hi[idx] = h; lo[idx] = l;
  }
}

__global__ void cvt_bias(const float* __restrict__ b1, const float* __restrict__ b2,
                         float* __restrict__ dst, int n, int npad){
  for (int i = blockIdx.x * blockDim.x + threadIdx.x; i < npad; i += gridDim.x * blockDim.x){
    float v = 0.f;
    if (i < n){ v = b1[i]; if (b2) v += b2[i]; }
    dst[i] = v;
  }
}

// inp split from x_enc[:, T-1, :], pad zeroed
__global__ void init_inp(const float* __restrict__ x_enc, u16* __restrict__ inph, u16* __restrict__ inpl){
  int total = BB * EPAD;
  for (int idx = blockIdx.x * blockDim.x + threadIdx.x; idx < total; idx += gridDim.x * blockDim.x){
    int b = idx / EPAD, j = idx - b * EPAD;
    float v = (j < EE) ? x_enc[(size_t)b * TT * EE + (size_t)(TT - 1) * EE + j] : 0.f;
    u16 h, l; splitf(v, h, l);
    inph[idx] = h; inpl[idx] = l;
  }
}

// pre-split x_enc [B][T][E] -> [T][B][EPAD] hi/lo
__global__ void split_xenc(const float* __restrict__ x, u16* __restrict__ xh, u16* __restrict__ xl){
  const int total = TT * BB * EPAD;
  for (int idx = blockIdx.x * blockDim.x + threadIdx.x; idx < total; idx += gridDim.x * blockDim.x){
    int e = idx % EPAD;
    int rest = idx / EPAD;
    int b = rest % BB;
    int t = rest / BB;
    float v = (e < EE) ? x[((size_t)b * TT + t) * EE + e] : 0.f;
    u16 h, l; splitf(v, h, l);
    xh[idx] = h; xl[idx] = l;
  }
}

// Wcomb[g][k] = sum_e Wd0ih[g][e] * fcW[e][k]   (fp32, one-time)
__global__ void wcomb(const float* __restrict__ A,   // [2048][321]
                      const float* __restrict__ Bm,  // [321][512]  (fc_W)
                      float* __restrict__ C){        // [2048][512]
  __shared__ float arow[EE];
  const int g = blockIdx.x;
  for (int e = threadIdx.x; e < EE; e += 256) arow[e] = A[(size_t)g * EE + e];
  __syncthreads();
  for (int k = threadIdx.x; k < HH; k += 256){
    float s = 0.f;
    for (int e = 0; e < EE; ++e) s += arow[e] * Bm[(size_t)e * HH + k];
    C[(size_t)g * HH + k] = s;
  }
}

// bd0c[g] = bd0[g] + sum_e Wd0ih[g][e] * fcb[e]
__global__ void bias_fold(const float* __restrict__ bd0, const float* __restrict__ A,
                          const float* __restrict__ fcb, float* __restrict__ out){
  int g = blockIdx.x * blockDim.x + threadIdx.x;
  if (g < G4){
    float s = bd0[g];
    for (int e = 0; e < EE; ++e) s += A[(size_t)g * EE + e] * fcb[e];
    out[g] = s;
  }
}

// ---------- LSTM cell body: tile M=128 batch x N=64 gate-cols (16 units x 4 gates) ----------
// (unchanged from round-1 — proven: global_load_lds double-buffer, counted vmcnt(6), XOR swizzle)
__device__ __forceinline__ void lstm_body(
    char* smem, int bx,
    const u16* __restrict__ Xh, const u16* __restrict__ Xl, int K1pad,
    const u16* __restrict__ Wih_h, const u16* __restrict__ Wih_l, // [2048][K1pad]
    const u16* __restrict__ Whh_h, const u16* __restrict__ Whh_l, // [2048][512]
    const float* __restrict__ bias,
    const u16* __restrict__ Hph, const u16* __restrict__ Hpl, // prev h split [512][512]
    u16* __restrict__ Hnh, u16* __restrict__ Hnl,             // next h split
    float* __restrict__ cst)                                  // c state fp32 [512][512]
{
  float (*sG)[68] = (float (*)[68])(smem);   // aliases staging; used only after final barrier

  const int tid  = threadIdx.x;
  const int lane = tid & 63;
  const int wid  = tid >> 6;
  const int wm = wid >> 1, wn = wid & 1;
  const int m0 = (bx >> 5) * 128;
  const int u0 = (bx & 31) * 16;

  floatx16 acc0 = {0.f,0.f,0.f,0.f,0.f,0.f,0.f,0.f,0.f,0.f,0.f,0.f,0.f,0.f,0.f,0.f};
  floatx16 acc1 = {0.f,0.f,0.f,0.f,0.f,0.f,0.f,0.f,0.f,0.f,0.f,0.f,0.f,0.f,0.f,0.f};

  const int ml    = lane & 31;
  const int thalf = lane >> 5;
  const int a0r = wm * 64 + ml;
  const int a1r = a0r + 32;
  const int brw = wn * 32 + ml;
  const int xa  = (a0r >> 1) & 3;
  const int xb  = (brw >> 1) & 3;

  const int sl  = lane & 3;
  const int rq  = lane >> 2;
  const int rx0 = wid * 32 + rq;
  const int rw  = wid * 16 + rq;
  const int sgx = (sl ^ ((rx0 >> 1) & 3)) << 4;
  const int sgw = (sl ^ ((rw  >> 1) & 3)) << 4;
  const size_t gxr0 = (size_t)(m0 + rx0);
  const size_t gxr1 = gxr0 + 16;
  const size_t gwr  = (size_t)wid * HH + u0 + rq;
  const int oX = wid * 32 * 64;
  const int oW = wid * 16 * 64;

  const int nch1 = K1pad >> 5;
  const int ncht = nch1 + (HH >> 5);

  auto stage = [&](int ch){
    const bool p1 = ch < nch1;
    const int k0 = (p1 ? ch : ch - nch1) << 5;
    const u16* xh = p1 ? Xh : Hph;
    const u16* xl = p1 ? Xl : Hpl;
    const u16* wh = p1 ? Wih_h : Whh_h;
    const u16* wl = p1 ? Wih_l : Whh_l;
    const size_t Kp = p1 ? (size_t)K1pad : (size_t)HH;
    char* b = smem + (ch & 1) * BUF_SZ;
    gload16((const char*)(xh + gxr0 * Kp + k0) + sgx, b + XH_OFF + oX);
    gload16((const char*)(xh + gxr1 * Kp + k0) + sgx, b + XH_OFF + oX + 1024);
    gload16((const char*)(xl + gxr0 * Kp + k0) + sgx, b + XL_OFF + oX);
    gload16((const char*)(xl + gxr1 * Kp + k0) + sgx, b + XL_OFF + oX + 1024);
    gload16((const char*)(wh + gwr  * Kp + k0) + sgw, b + WH_OFF + oW);
    gload16((const char*)(wl + gwr  * Kp + k0) + sgw, b + WL_OFF + oW);
  };

  stage(0);
  for (int ch = 0; ch < ncht; ++ch){
    if (ch + 1 < ncht) stage(ch + 1);
    __builtin_amdgcn_sched_barrier(0);
    if (ch + 1 < ncht) { asm volatile("s_waitcnt vmcnt(6)" ::: "memory"); }
    else               { asm volatile("s_waitcnt vmcnt(0)" ::: "memory"); }
    __builtin_amdgcn_s_barrier();
    __builtin_amdgcn_sched_barrier(0);
    const char* bufc = smem + (ch & 1) * BUF_SZ;
    #pragma unroll
    for (int kk2 = 0; kk2 < 2; ++kk2){
      const int t0 = kk2 * 2 + thalf;
      bf16x8 ah0 = *(const bf16x8*)(bufc + XH_OFF + a0r * 64 + ((t0 ^ xa) << 4));
      bf16x8 al0 = *(const bf16x8*)(bufc + XL_OFF + a0r * 64 + ((t0 ^ xa) << 4));
      bf16x8 ah1 = *(const bf16x8*)(bufc + XH_OFF + a1r * 64 + ((t0 ^ xa) << 4));
      bf16x8 al1 = *(const bf16x8*)(bufc + XL_OFF + a1r * 64 + ((t0 ^ xa) << 4));
      bf16x8 bh  = *(const bf16x8*)(bufc + WH_OFF + brw * 64 + ((t0 ^ xb) << 4));
      bf16x8 bl  = *(const bf16x8*)(bufc + WL_OFF + brw * 64 + ((t0 ^ xb) << 4));
      acc0 = __builtin_amdgcn_mfma_f32_32x32x16_bf16(ah0, bh, acc0, 0, 0, 0);
      acc0 = __builtin_amdgcn_mfma_f32_32x32x16_bf16(ah0, bl, acc0, 0, 0, 0);
      acc0 = __builtin_amdgcn_mfma_f32_32x32x16_bf16(al0, bh, acc0, 0, 0, 0);
      acc1 = __builtin_amdgcn_mfma_f32_32x32x16_bf16(ah1, bh, acc1, 0, 0, 0);
      acc1 = __builtin_amdgcn_mfma_f32_32x32x16_bf16(ah1, bl, acc1, 0, 0, 0);
      acc1 = __builtin_amdgcn_mfma_f32_32x32x16_bf16(al1, bh, acc1, 0, 0, 0);
    }
    __builtin_amdgcn_sched_barrier(0);
    asm volatile("s_waitcnt lgkmcnt(0)" ::: "memory");
    __builtin_amdgcn_s_barrier();
    __builtin_amdgcn_sched_barrier(0);
  }
  __syncthreads();

  // ---- epilogue: gate exchange via LDS (aliased), cell update, split-write h ----
  #pragma unroll
  for (int r = 0; r < 16; ++r){
    const int mm = (r & 3) + 8 * (r >> 2) + 4 * thalf;
    sG[wm * 64 + mm][wn * 32 + ml]      = acc0[r];
    sG[wm * 64 + 32 + mm][wn * 32 + ml] = acc1[r];
  }
  __syncthreads();
  for (int e = tid; e < 2048; e += 256){
    const int m = e >> 4, u = e & 15;
    const int gj = u0 + u;
    const float gi = sG[m][u]      + bias[gj];
    const float gf = sG[m][16 + u] + bias[HH + gj];
    const float gg = sG[m][32 + u] + bias[2 * HH + gj];
    const float go = sG[m][48 + u] + bias[3 * HH + gj];
    const float si = 1.f / (1.f + expf(-gi));
    const float sf = 1.f / (1.f + expf(-gf));
    const float so = 1.f / (1.f + expf(-go));
    const size_t sidx = (size_t)(m0 + m) * HH + gj;
    const float cn = sf * cst[sidx] + si * tanhf(gg);
    const float hn = so * tanhf(cn);
    cst[sidx] = cn;
    u16 hh, hl; splitf(hn, hh, hl);
    Hnh[sidx] = hh; Hnl[sidx] = hl;
  }
  __syncthreads();  // block done with sG before next body call reuses smem
}

// ---------- encoder: single cooperative kernel, 97 iterations, 1 grid sync each ----------
// blocks [0,128) = cell0(t), [128,256) = cell1(t-1)
__global__ __launch_bounds__(256) void enc_coop(
    const u16* Xench, const u16* Xencl,
    const u16* We0ih_h, const u16* We0ih_l, const u16* We0hh_h, const u16* We0hh_l,
    const float* be0,
    u16* h0h0, u16* h0l0, u16* h0h1, u16* h0l1, float* c0,
    const u16* We1ih_h, const u16* We1ih_l, const u16* We1hh_h, const u16* We1hh_l,
    const float* be1,
    u16* h1h0, u16* h1l0, u16* h1h1, u16* h1l1, float* c1)
{
  extern __shared__ char smem[];
  cg::grid_group grid = cg::this_grid();
  const int half = blockIdx.x >> 7;
  const int bx   = blockIdx.x & 127;
  for (int t = 0; t <= TT; ++t){
    const int rd = t & 1;
    u16* h0rh = rd ? h0h1 : h0h0;  u16* h0rl = rd ? h0l1 : h0l0;
    u16* h0wh = rd ? h0h0 : h0h1;  u16* h0wl = rd ? h0l0 : h0l1;
    u16* h1rh = rd ? h1h1 : h1h0;  u16* h1rl = rd ? h1l1 : h1l0;
    u16* h1wh = rd ? h1h0 : h1h1;  u16* h1wl = rd ? h1l0 : h1l1;
    if (half == 0){
      if (t < TT)
        lstm_body(smem, bx, Xench + (size_t)t * BB * EPAD, Xencl + (size_t)t * BB * EPAD, EPAD,
                  We0ih_h, We0ih_l, We0hh_h, We0hh_l, be0,
                  h0rh, h0rl, h0wh, h0wl, c0);
    } else {
      if (t > 0)
        lstm_body(smem, bx, h0rh, h0rl, HH,
                  We1ih_h, We1ih_l, We1hh_h, We1hh_l, be1,
                  h1wh, h1wl, h1rh, h1rl, c1);
    }
    grid.sync();
  }
  // finals land at parity 0 for both h0 and h1
}

// ---------- decoder: single cooperative kernel (fc folded into cell0 via Wcomb) ----------
// per step: cell0 -> grid sync -> cell1 (writes h1 history slab) -> grid sync. 128 blocks.
__global__ __launch_bounds__(256) void dec_coop(
    const u16* inph, const u16* inpl,
    const u16* Wd0ih_h, const u16* Wd0ih_l,   // p=0 path (K=EPAD)
    const u16* Wc_h, const u16* Wc_l,         // p>=1 path: Wd0ih @ fcW (K=HH)
    const u16* Wd0hh_h, const u16* Wd0hh_l,
    const float* bd0, const float* bd0c,
    u16* h0h0, u16* h0l0, u16* h0h1, u16* h0l1, float* c0,
    const u16* Wd1ih_h, const u16* Wd1ih_l,
    const u16* Wd1hh_h, const u16* Wd1hh_l,
    const float* bd1,
    const u16* h1h0, const u16* h1l0,         // encoder-final h1
    u16* histh, u16* histl, float* c1)        // h1 history [PP][BB][HH]
{
  extern __shared__ char smem[];
  cg::grid_group grid = cg::this_grid();
  const int bx = blockIdx.x;
  const size_t S = (size_t)BB * HH;
  for (int p = 0; p < PP; ++p){
    const int rd = p & 1;
    u16* h0rh = rd ? h0h1 : h0h0;  u16* h0rl = rd ? h0l1 : h0l0;
    u16* h0wh = rd ? h0h0 : h0h1;  u16* h0wl = rd ? h0l0 : h0l1;
    const u16* hp_h = p ? histh + (size_t)(p - 1) * S : h1h0;
    const u16* hp_l = p ? histl + (size_t)(p - 1) * S : h1l0;
    // cell0: gates = X @ W0^T + h0_prev @ Whh0^T ; X = inp0 (p=0) or h1(p-1) via Wcomb
    lstm_body(smem, bx,
              p ? hp_h : inph, p ? hp_l : inpl, p ? HH : EPAD,
              p ? Wc_h : Wd0ih_h, p ? Wc_l : Wd0ih_l,
              Wd0hh_h, Wd0hh_l,
              p ? bd0c : bd0,
              h0rh, h0rl, h0wh, h0wl, c0);
    grid.sync();
    // cell1: X = h0(p), H = h1(p-1); writes history slab p
    lstm_body(smem, bx,
              h0wh, h0wl, HH,
              Wd1ih_h, Wd1ih_l, Wd1hh_h, Wd1hh_l, bd1,
              hp_h, hp_l,
              histh + (size_t)p * S, histl + (size_t)p * S, c1);
    grid.sync();
  }
}

// ---------- batched FC: out[b][p][:] = hist[p][b] @ fcW^T + fcb, all 96 steps at once ----------
__global__ __launch_bounds__(256) void fc_batch(
    const u16* __restrict__ Hh, const u16* __restrict__ Hl,   // [PP*BB][512]
    const u16* __restrict__ Wh, const u16* __restrict__ Wl,   // [384][512]
    const float* __restrict__ bfc,
    float* __restrict__ out)
{
  extern __shared__ char smem[];
  const int tid = threadIdx.x, lane = tid & 63, wid = tid >> 6;
  const int wm = wid >> 1, wn = wid & 1;
  const int m0 = blockIdx.x * 128;      // row = p*512 + b
  const int n0 = blockIdx.y * 64;

  floatx16 acc0 = {0.f,0.f,0.f,0.f,0.f,0.f,0.f,0.f,0.f,0.f,0.f,0.f,0.f,0.f,0.f,0.f};
  floatx16 acc1 = {0.f,0.f,0.f,0.f,0.f,0.f,0.f,0.f,0.f,0.f,0.f,0.f,0.f,0.f,0.f,0.f};

  const int ml    = lane & 31;
  const int thalf = lane >> 5;
  const int a0r = wm * 64 + ml;
  const int a1r = a0r + 32;
  const int brw = wn * 32 + ml;
  const int xa  = (a0r >> 1) & 3;
  const int xb  = (brw >> 1) & 3;

  const int sl  = lane & 3;
  const int rq  = lane >> 2;
  const int rx0 = wid * 32 + rq;
  const int rw  = wid * 16 + rq;
  const int sgx = (sl ^ ((rx0 >> 1) & 3)) << 4;
  const int sgw = (sl ^ ((rw  >> 1) & 3)) << 4;
  const size_t gxr0 = (size_t)(m0 + rx0);
  const size_t gxr1 = gxr0 + 16;
  const size_t gwr  = (size_t)(n0 + rw);
  const int oX = wid * 32 * 64;
  const int oW = wid * 16 * 64;

  auto stage = [&](int ch){
    const int k0 = ch << 5;
    char* b = smem + (ch & 1) * BUF_SZ;
    gload16((const char*)(Hh + gxr0 * HH + k0) + sgx, b + XH_OFF + oX);
    gload16((const char*)(Hh + gxr1 * HH + k0) + sgx, b + XH_OFF + oX + 1024);
    gload16((const char*)(Hl + gxr0 * HH + k0) + sgx, b + XL_OFF + oX);
    gload16((const char*)(Hl + gxr1 * HH + k0) + sgx, b + XL_OFF + oX + 1024);
    gload16((const char*)(Wh + gwr  * HH + k0) + sgw, b + WH_OFF + oW);
    gload16((const char*)(Wl + gwr  * HH + k0) + sgw, b + WL_OFF + oW);
  };

  stage(0);
  for (int ch = 0; ch < 16; ++ch){
    if (ch + 1 < 16) stage(ch + 1);
    __builtin_amdgcn_sched_barrier(0);
    if (ch + 1 < 16) { asm volatile("s_waitcnt vmcnt(6)" ::: "memory"); }
    else             { asm volatile("s_waitcnt vmcnt(0)" ::: "memory"); }
    __builtin_amdgcn_s_barrier();
    __builtin_amdgcn_sched_barrier(0);
    const char* bufc = smem + (ch & 1) * BUF_SZ;
    #pragma unroll
    for (int kk2 = 0; kk2 < 2; ++kk2){
      const int t0 = kk2 * 2 + thalf;
      bf16x8 ah0 = *(const bf16x8*)(bufc + XH_OFF + a0r * 64 + ((t0 ^ xa) << 4));
      bf16x8 al0 = *(const bf16x8*)(bufc + XL_OFF + a0r * 64 + ((t0 ^ xa) << 4));
      bf16x8 ah1 = *(const bf16x8*)(bufc + XH_OFF + a1r * 64 + ((t0 ^ xa) << 4));
      bf16x8 al1 = *(const bf16x8*)(bufc + XL_OFF + a1r * 64 + ((t0 ^ xa) << 4));
      bf16x8 bh  = *(const bf16x8*)(bufc + WH_OFF + brw * 64 + ((t0 ^ xb) << 4));
      bf16x8 bl  = *(const bf16x8*)(bufc + WL_OFF + brw * 64 + ((t0 ^ xb) << 4));
      acc0 = __builtin_amdgcn_mfma_f32_32x32x16_bf16(ah0, bh, acc0, 0, 0, 0);
      acc0 = __builtin_amdgcn_mfma_f32_32x32x16_bf16(ah0, bl, acc0, 0, 0, 0);
      acc0 = __builtin_amdgcn_mfma_f32_32x32x16_bf16(al0, bh, acc0, 0, 0, 0);
      acc1 = __builtin_amdgcn_mfma_f32_32x32x16_bf16(ah1, bh, acc1, 0, 0, 0);
      acc1 = __builtin_amdgcn_mfma_f32_32x32x16_bf16(ah1, bl, acc1, 0, 0, 0);
      acc1 = __builtin_amdgcn_mfma_f32_32x32x16_bf16(al1, bh, acc1, 0, 0, 0);
    }
    __builtin_amdgcn_sched_barrier(0);
    asm volatile("s_waitcnt lgkmcnt(0)" ::: "memory");
    __builtin_amdgcn_s_barrier();
    __builtin_amdgcn_sched_barrier(0);
  }

  const int n = n0 + wn * 32 + ml;
  if (n < CC){
    const float bv = bfc[n];
    #pragma unroll
    for (int r = 0; r < 16; ++r){
      const int mm = (r & 3) + 8 * (r >> 2) + 4 * thalf;
      {
        const int rr = m0 + wm * 64 + mm;              // p*512 + b
        out[(size_t)(rr & 511) * PP * CC + (size_t)(rr >> 9) * CC + n] = acc0[r] + bv;
      }
      {
        const int rr = m0 + wm * 64 + 32 + mm;
        out[(size_t)(rr & 511) * PP * CC + (size_t)(rr >> 9) * CC + n] = acc1[r] + bv;
      }
    }
  }
}

extern "C" void kernel_launch(void* const* d_in, const int* in_sizes, int n_in,
                              void* d_out, int out_size, void* d_ws, size_t ws_size,
                              hipStream_t stream) {
  const float* x_enc  = (const float*)d_in[0];
  const float* e_Wih0 = (const float*)d_in[4];
  const float* e_Whh0 = (const float*)d_in[5];
  const float* e_bih0 = (const float*)d_in[6];
  const float* e_bhh0 = (const float*)d_in[7];
  const float* e_Wih1 = (const float*)d_in[8];
  const float* e_Whh1 = (const float*)d_in[9];
  const float* e_bih1 = (const float*)d_in[10];
  const float* e_bhh1 = (const float*)d_in[11];
  const float* d_Wih0 = (const float*)d_in[12];
  const float* d_Whh0 = (const float*)d_in[13];
  const float* d_bih0 = (const float*)d_in[14];
  const float* d_bhh0 = (const float*)d_in[15];
  const float* d_Wih1 = (const float*)d_in[16];
  const float* d_Whh1 = (const float*)d_in[17];
  const float* d_bih1 = (const float*)d_in[18];
  const float* d_bhh1 = (const float*)d_in[19];
  const float* fc_W   = (const float*)d_in[20];
  const float* fc_b   = (const float*)d_in[21];

  char* base = (char*)d_ws;
  size_t off = 0;
  auto alloc_us = [&](size_t n){ u16* p = (u16*)(base + off); off += ((n * 2 + 15) & ~(size_t)15); return p; };
  auto alloc_f  = [&](size_t n){ float* p = (float*)(base + off); off += ((n * 4 + 15) & ~(size_t)15); return p; };

  u16 *We0ih_h = alloc_us((size_t)G4 * EPAD), *We0ih_l = alloc_us((size_t)G4 * EPAD);
  u16 *We0hh_h = alloc_us((size_t)G4 * HH),   *We0hh_l = alloc_us((size_t)G4 * HH);
  u16 *We1ih_h = alloc_us((size_t)G4 * HH),   *We1ih_l = alloc_us((size_t)G4 * HH);
  u16 *We1hh_h = alloc_us((size_t)G4 * HH),   *We1hh_l = alloc_us((size_t)G4 * HH);
  u16 *Wd0ih_h = alloc_us((size_t)G4 * EPAD), *Wd0ih_l = alloc_us((size_t)G4 * EPAD);
  u16 *Wd0hh_h = alloc_us((size_t)G4 * HH),   *Wd0hh_l = alloc_us((size_t)G4 * HH);
  u16 *Wd1ih_h = alloc_us((size_t)G4 * HH),   *Wd1ih_l = alloc_us((size_t)G4 * HH);
  u16 *Wd1hh_h = alloc_us((size_t)G4 * HH),   *Wd1hh_l = alloc_us((size_t)G4 * HH);
  u16 *Wfc_h   = alloc_us((size_t)NFC * HH),  *Wfc_l   = alloc_us((size_t)NFC * HH);
  u16 *Wc_h    = alloc_us((size_t)G4 * HH),   *Wc_l    = alloc_us((size_t)G4 * HH);
  float* be0 = alloc_f(G4);
  float* be1 = alloc_f(G4);
  float* bd0 = alloc_f(G4);
  float* bd1 = alloc_f(G4);
  float* bfc = alloc_f(NFC);
  float* bd0c = alloc_f(G4);
  float* Wcf32 = alloc_f((size_t)G4 * HH);
  // zero-init region: h0[0], h1[0] (hi+lo) then c0, c1 — one memset covers all
  u16* h0h[2]; u16* h0l[2]; u16* h1h[2]; u16* h1l[2];
  h0h[0] = alloc_us((size_t)BB * HH); h0l[0] = alloc_us((size_t)BB * HH);
  h1h[0] = alloc_us((size_t)BB * HH); h1l[0] = alloc_us((size_t)BB * HH);
  float* c0 = alloc_f((size_t)BB * HH);
  float* c1 = alloc_f((size_t)BB * HH);
  h0h[1] = alloc_us((size_t)BB * HH); h0l[1] = alloc_us((size_t)BB * HH);
  h1h[1] = alloc_us((size_t)BB * HH); h1l[1] = alloc_us((size_t)BB * HH);
  u16* inph = alloc_us((size_t)BB * EPAD);
  u16* inpl = alloc_us((size_t)BB * EPAD);
  u16* Xench = alloc_us((size_t)TT * BB * EPAD);
  u16* Xencl = alloc_us((size_t)TT * BB * EPAD);
  u16* histh = alloc_us((size_t)PP * BB * HH);
  u16* histl = alloc_us((size_t)PP * BB * HH);

  // prep (every launch; ws re-poisoned by harness)
  cvt_split<<<512, 256, 0, stream>>>(e_Wih0, We0ih_h, We0ih_l, G4, EE, G4, EPAD);
  cvt_split<<<512, 256, 0, stream>>>(e_Whh0, We0hh_h, We0hh_l, G4, HH, G4, HH);
  cvt_split<<<512, 256, 0, stream>>>(e_Wih1, We1ih_h, We1ih_l, G4, HH, G4, HH);
  cvt_split<<<512, 256, 0, stream>>>(e_Whh1, We1hh_h, We1hh_l, G4, HH, G4, HH);
  cvt_split<<<512, 256, 0, stream>>>(d_Wih0, Wd0ih_h, Wd0ih_l, G4, EE, G4, EPAD);
  cvt_split<<<512, 256, 0, stream>>>(d_Whh0, Wd0hh_h, Wd0hh_l, G4, HH, G4, HH);
  cvt_split<<<512, 256, 0, stream>>>(d_Wih1, Wd1ih_h, Wd1ih_l, G4, HH, G4, HH);
  cvt_split<<<512, 256, 0, stream>>>(d_Whh1, Wd1hh_h, Wd1hh_l, G4, HH, G4, HH);
  cvt_split<<<512, 256, 0, stream>>>(fc_W,   Wfc_h,   Wfc_l,   CC, HH, NFC, HH);
  cvt_bias<<<8, 256, 0, stream>>>(e_bih0, e_bhh0, be0, G4, G4);
  cvt_bias<<<8, 256, 0, stream>>>(e_bih1, e_bhh1, be1, G4, G4);
  cvt_bias<<<8, 256, 0, stream>>>(d_bih0, d_bhh0, bd0, G4, G4);
  cvt_bias<<<8, 256, 0, stream>>>(d_bih1, d_bhh1, bd1, G4, G4);
  cvt_bias<<<2, 256, 0, stream>>>(fc_b, nullptr, bfc, CC, NFC);
  // fc folding: Wcomb = Wd0ih @ fcW (fp32), bd0c = bd0 + Wd0ih @ fcb
  wcomb<<<G4, 256, 0, stream>>>(d_Wih0, fc_W, Wcf32);
  bias_fold<<<8, 256, 0, stream>>>(bd0, d_Wih0, fc_b, bd0c);
  cvt_split<<<512, 256, 0, stream>>>(Wcf32, Wc_h, Wc_l, G4, HH, G4, HH);
  hipMemsetAsync(h0h[0], 0, (size_t)4 * BB * HH * sizeof(u16) + (size_t)2 * BB * HH * sizeof(float), stream);
  init_inp<<<512, 256, 0, stream>>>(x_enc, inph, inpl);
  split_xenc<<<4096, 256, 0, stream>>>(x_enc, Xench, Xencl);

  // encoder: one cooperative kernel (97 iterations, 1 grid sync each)
  {
    void* args[] = { (void*)&Xench, (void*)&Xencl,
                     (void*)&We0ih_h, (void*)&We0ih_l, (void*)&We0hh_h, (void*)&We0hh_l,
                     (void*)&be0,
                     (void*)&h0h[0], (void*)&h0l[0], (void*)&h0h[1], (void*)&h0l[1], (void*)&c0,
                     (void*)&We1ih_h, (void*)&We1ih_l, (void*)&We1hh_h, (void*)&We1hh_l,
                     (void*)&be1,
                     (void*)&h1h[0], (void*)&h1l[0], (void*)&h1h[1], (void*)&h1l[1], (void*)&c1 };
    hipLaunchCooperativeKernel((const void*)enc_coop, dim3(256), dim3(256), args, LSTM_SMEM, stream);
  }

  // decoder: one cooperative kernel (96 steps x {cell0, cell1}, fc folded)
  {
    void* args[] = { (void*)&inph, (void*)&inpl,
                     (void*)&Wd0ih_h, (void*)&Wd0ih_l,
                     (void*)&Wc_h, (void*)&Wc_l,
                     (void*)&Wd0hh_h, (void*)&Wd0hh_l,
                     (void*)&bd0, (void*)&bd0c,
                     (void*)&h0h[0], (void*)&h0l[0], (void*)&h0h[1], (void*)&h0l[1], (void*)&c0,
                     (void*)&Wd1ih_h, (void*)&Wd1ih_l, (void*)&Wd1hh_h, (void*)&Wd1hh_l,
                     (void*)&bd1,
                     (void*)&h1h[0], (void*)&h1l[0],
                     (void*)&histh, (void*)&histl, (void*)&c1 };
    hipLaunchCooperativeKernel((const void*)dec_coop, dim3(128), dim3(256), args, LSTM_SMEM, stream);
  }

  // batched FC over all 96 decoder steps
  fc_batch<<<dim3((PP * BB) / 128, NFC / 64), 256, LSTM_SMEM, stream>>>(
      histh, histl, Wfc_h, Wfc_l, bfc, (float*)d_out);
}

// Round 3
// 7680.143 us; speedup vs baseline: 1.6616x; 1.6616x over previous
//
#include <hip/hip_runtime.h>
#include <hip/hip_bf16.h>

#define BB 512     // batch
#define TT 96      // encoder steps
#define PP 96      // decoder steps
#define EE 321     // input features
#define CC 321     // output channels
#define HH 512     // hidden
#define G4 2048    // 4*H
#define EPAD 352   // 321 padded to 32
#define NFC 384    // fc N pad (64-multiple)

// double-buffered LDS staging: per buffer Xh[128][32] Xl[128][32] Wh[64][32] Wl[64][32] (u16)
#define BUF_SZ 24576
#define XH_OFF 0
#define XL_OFF 8192
#define WH_OFF 16384
#define WL_OFF 20480
#define LSTM_SMEM 49152  // 2 buffers; sG (34816 B) aliases after final barrier

typedef unsigned short u16;
typedef __attribute__((ext_vector_type(8))) short bf16x8;
typedef __attribute__((ext_vector_type(16))) float floatx16;

__device__ __forceinline__ void splitf(float v, u16& h, u16& l){
  __hip_bfloat16 bh = __float2bfloat16(v);
  h = *reinterpret_cast<u16*>(&bh);
  float r = v - __bfloat162float(bh);
  __hip_bfloat16 bl = __float2bfloat16(r);
  l = *reinterpret_cast<u16*>(&bl);
}

// async global->LDS, 16B per lane; LDS dest = wave-uniform base + lane*16 (linear).
__device__ __forceinline__ void gload16(const void* g, void* l){
  __builtin_amdgcn_global_load_lds((const __attribute__((address_space(1))) void*)g,
                                   (__attribute__((address_space(3))) void*)l, 16, 0, 0);
}

// ---------- prep: split fp32 [rows][cols] -> bf16 hi/lo [rowspad][colspad] ----------
__global__ void cvt_split(const float* __restrict__ src, u16* __restrict__ hi, u16* __restrict__ lo,
                          int rows, int cols, int rowspad, int colspad){
  int total = rowspad * colspad;
  for (int idx = blockIdx.x * blockDim.x + threadIdx.x; idx < total; idx += gridDim.x * blockDim.x){
    int r = idx / colspad, cc = idx - r * colspad;
    float v = (r < rows && cc < cols) ? src[(size_t)r * cols + cc] : 0.f;
    u16 h, l; splitf(v, h, l);
    hi[idx] = h; lo[idx] = l;
  }
}

__global__ void cvt_bias(const float* __restrict__ b1, const float* __restrict__ b2,
                         float* __restrict__ dst, int n, int npad){
  for (int i = blockIdx.x * blockDim.x + threadIdx.x; i < npad; i += gridDim.x * blockDim.x){
    float v = 0.f;
    if (i < n){ v = b1[i]; if (b2) v += b2[i]; }
    dst[i] = v;
  }
}

// inp split from x_enc[:, T-1, :], pad zeroed
__global__ void init_inp(const float* __restrict__ x_enc, u16* __restrict__ inph, u16* __restrict__ inpl){
  int total = BB * EPAD;
  for (int idx = blockIdx.x * blockDim.x + threadIdx.x; idx < total; idx += gridDim.x * blockDim.x){
    int b = idx / EPAD, j = idx - b * EPAD;
    float v = (j < EE) ? x_enc[(size_t)b * TT * EE + (size_t)(TT - 1) * EE + j] : 0.f;
    u16 h, l; splitf(v, h, l);
    inph[idx] = h; inpl[idx] = l;
  }
}

// pre-split x_enc [B][T][E] -> [T][B][EPAD] hi/lo
__global__ void split_xenc(const float* __restrict__ x, u16* __restrict__ xh, u16* __restrict__ xl){
  const int total = TT * BB * EPAD;
  for (int idx = blockIdx.x * blockDim.x + threadIdx.x; idx < total; idx += gridDim.x * blockDim.x){
    int e = idx % EPAD;
    int rest = idx / EPAD;
    int b = rest % BB;
    int t = rest / BB;
    float v = (e < EE) ? x[((size_t)b * TT + t) * EE + e] : 0.f;
    u16 h, l; splitf(v, h, l);
    xh[idx] = h; xl[idx] = l;
  }
}

// Wcomb[g][k] = sum_e Wd0ih[g][e] * fcW[e][k]   (fp32, one-time)
__global__ void wcomb(const float* __restrict__ A,   // [2048][321]
                      const float* __restrict__ Bm,  // [321][512]  (fc_W)
                      float* __restrict__ C){        // [2048][512]
  __shared__ float arow[EE];
  const int g = blockIdx.x;
  for (int e = threadIdx.x; e < EE; e += 256) arow[e] = A[(size_t)g * EE + e];
  __syncthreads();
  for (int k = threadIdx.x; k < HH; k += 256){
    float s = 0.f;
    for (int e = 0; e < EE; ++e) s += arow[e] * Bm[(size_t)e * HH + k];
    C[(size_t)g * HH + k] = s;
  }
}

// bd0c[g] = bd0[g] + sum_e Wd0ih[g][e] * fcb[e]
__global__ void bias_fold(const float* __restrict__ bd0, const float* __restrict__ A,
                          const float* __restrict__ fcb, float* __restrict__ out){
  int g = blockIdx.x * blockDim.x + threadIdx.x;
  if (g < G4){
    float s = bd0[g];
    for (int e = 0; e < EE; ++e) s += A[(size_t)g * EE + e] * fcb[e];
    out[g] = s;
  }
}

// ---------- LSTM cell body: tile M=128 batch x N=64 gate-cols (16 units x 4 gates) ----------
// Proven round-1 body: global_load_lds double-buffer, counted vmcnt(6), XOR swizzle.
__device__ __forceinline__ void lstm_body(
    char* smem, int bx,
    const u16* __restrict__ Xh, const u16* __restrict__ Xl, int K1pad,
    const u16* __restrict__ Wih_h, const u16* __restrict__ Wih_l, // [2048][K1pad]
    const u16* __restrict__ Whh_h, const u16* __restrict__ Whh_l, // [2048][512]
    const float* __restrict__ bias,
    const u16* __restrict__ Hph, const u16* __restrict__ Hpl, // prev h split [512][512]
    u16* __restrict__ Hnh, u16* __restrict__ Hnl,             // next h split
    float* __restrict__ cst)                                  // c state fp32 [512][512]
{
  float (*sG)[68] = (float (*)[68])(smem);   // aliases staging; used only after final barrier

  const int tid  = threadIdx.x;
  const int lane = tid & 63;
  const int wid  = tid >> 6;
  const int wm = wid >> 1, wn = wid & 1;
  const int m0 = (bx >> 5) * 128;
  const int u0 = (bx & 31) * 16;

  floatx16 acc0 = {0.f,0.f,0.f,0.f,0.f,0.f,0.f,0.f,0.f,0.f,0.f,0.f,0.f,0.f,0.f,0.f};
  floatx16 acc1 = {0.f,0.f,0.f,0.f,0.f,0.f,0.f,0.f,0.f,0.f,0.f,0.f,0.f,0.f,0.f,0.f};

  const int ml    = lane & 31;
  const int thalf = lane >> 5;
  const int a0r = wm * 64 + ml;
  const int a1r = a0r + 32;
  const int brw = wn * 32 + ml;
  const int xa  = (a0r >> 1) & 3;
  const int xb  = (brw >> 1) & 3;

  const int sl  = lane & 3;
  const int rq  = lane >> 2;
  const int rx0 = wid * 32 + rq;
  const int rw  = wid * 16 + rq;
  const int sgx = (sl ^ ((rx0 >> 1) & 3)) << 4;
  const int sgw = (sl ^ ((rw  >> 1) & 3)) << 4;
  const size_t gxr0 = (size_t)(m0 + rx0);
  const size_t gxr1 = gxr0 + 16;
  const size_t gwr  = (size_t)wid * HH + u0 + rq;
  const int oX = wid * 32 * 64;
  const int oW = wid * 16 * 64;

  const int nch1 = K1pad >> 5;
  const int ncht = nch1 + (HH >> 5);

  auto stage = [&](int ch){
    const bool p1 = ch < nch1;
    const int k0 = (p1 ? ch : ch - nch1) << 5;
    const u16* xh = p1 ? Xh : Hph;
    const u16* xl = p1 ? Xl : Hpl;
    const u16* wh = p1 ? Wih_h : Whh_h;
    const u16* wl = p1 ? Wih_l : Whh_l;
    const size_t Kp = p1 ? (size_t)K1pad : (size_t)HH;
    char* b = smem + (ch & 1) * BUF_SZ;
    gload16((const char*)(xh + gxr0 * Kp + k0) + sgx, b + XH_OFF + oX);
    gload16((const char*)(xh + gxr1 * Kp + k0) + sgx, b + XH_OFF + oX + 1024);
    gload16((const char*)(xl + gxr0 * Kp + k0) + sgx, b + XL_OFF + oX);
    gload16((const char*)(xl + gxr1 * Kp + k0) + sgx, b + XL_OFF + oX + 1024);
    gload16((const char*)(wh + gwr  * Kp + k0) + sgw, b + WH_OFF + oW);
    gload16((const char*)(wl + gwr  * Kp + k0) + sgw, b + WL_OFF + oW);
  };

  stage(0);
  for (int ch = 0; ch < ncht; ++ch){
    if (ch + 1 < ncht) stage(ch + 1);
    __builtin_amdgcn_sched_barrier(0);
    if (ch + 1 < ncht) { asm volatile("s_waitcnt vmcnt(6)" ::: "memory"); }
    else               { asm volatile("s_waitcnt vmcnt(0)" ::: "memory"); }
    __builtin_amdgcn_s_barrier();
    __builtin_amdgcn_sched_barrier(0);
    const char* bufc = smem + (ch & 1) * BUF_SZ;
    #pragma unroll
    for (int kk2 = 0; kk2 < 2; ++kk2){
      const int t0 = kk2 * 2 + thalf;
      bf16x8 ah0 = *(const bf16x8*)(bufc + XH_OFF + a0r * 64 + ((t0 ^ xa) << 4));
      bf16x8 al0 = *(const bf16x8*)(bufc + XL_OFF + a0r * 64 + ((t0 ^ xa) << 4));
      bf16x8 ah1 = *(const bf16x8*)(bufc + XH_OFF + a1r * 64 + ((t0 ^ xa) << 4));
      bf16x8 al1 = *(const bf16x8*)(bufc + XL_OFF + a1r * 64 + ((t0 ^ xa) << 4));
      bf16x8 bh  = *(const bf16x8*)(bufc + WH_OFF + brw * 64 + ((t0 ^ xb) << 4));
      bf16x8 bl  = *(const bf16x8*)(bufc + WL_OFF + brw * 64 + ((t0 ^ xb) << 4));
      acc0 = __builtin_amdgcn_mfma_f32_32x32x16_bf16(ah0, bh, acc0, 0, 0, 0);
      acc0 = __builtin_amdgcn_mfma_f32_32x32x16_bf16(ah0, bl, acc0, 0, 0, 0);
      acc0 = __builtin_amdgcn_mfma_f32_32x32x16_bf16(al0, bh, acc0, 0, 0, 0);
      acc1 = __builtin_amdgcn_mfma_f32_32x32x16_bf16(ah1, bh, acc1, 0, 0, 0);
      acc1 = __builtin_amdgcn_mfma_f32_32x32x16_bf16(ah1, bl, acc1, 0, 0, 0);
      acc1 = __builtin_amdgcn_mfma_f32_32x32x16_bf16(al1, bh, acc1, 0, 0, 0);
    }
    __builtin_amdgcn_sched_barrier(0);
    asm volatile("s_waitcnt lgkmcnt(0)" ::: "memory");
    __builtin_amdgcn_s_barrier();
    __builtin_amdgcn_sched_barrier(0);
  }
  __syncthreads();

  // ---- epilogue: gate exchange via LDS (aliased), cell update, split-write h ----
  #pragma unroll
  for (int r = 0; r < 16; ++r){
    const int mm = (r & 3) + 8 * (r >> 2) + 4 * thalf;
    sG[wm * 64 + mm][wn * 32 + ml]      = acc0[r];
    sG[wm * 64 + 32 + mm][wn * 32 + ml] = acc1[r];
  }
  __syncthreads();
  for (int e = tid; e < 2048; e += 256){
    const int m = e >> 4, u = e & 15;
    const int gj = u0 + u;
    const float gi = sG[m][u]      + bias[gj];
    const float gf = sG[m][16 + u] + bias[HH + gj];
    const float gg = sG[m][32 + u] + bias[2 * HH + gj];
    const float go = sG[m][48 + u] + bias[3 * HH + gj];
    const float si = 1.f / (1.f + expf(-gi));
    const float sf = 1.f / (1.f + expf(-gf));
    const float so = 1.f / (1.f + expf(-go));
    const size_t sidx = (size_t)(m0 + m) * HH + gj;
    const float cn = sf * cst[sidx] + si * tanhf(gg);
    const float hn = so * tanhf(cn);
    cst[sidx] = cn;
    u16 hh, hl; splitf(hn, hh, hl);
    Hnh[sidx] = hh; Hnl[sidx] = hl;
  }
}

__global__ __launch_bounds__(256) void lstm_one(
    const u16* Xh, const u16* Xl, int K1pad,
    const u16* Wih_h, const u16* Wih_l, const u16* Whh_h, const u16* Whh_l,
    const float* bias, const u16* Hph, const u16* Hpl,
    u16* Hnh, u16* Hnl, float* cst)
{
  extern __shared__ char smem[];
  lstm_body(smem, blockIdx.x, Xh, Xl, K1pad,
            Wih_h, Wih_l, Whh_h, Whh_l, bias, Hph, Hpl, Hnh, Hnl, cst);
}

// Fused encoder step: blocks [0,128) = cell0(t), [128,256) = cell1(t-1).
__global__ __launch_bounds__(256) void lstm_pair(
    int act0, const u16* X0h, const u16* X0l,
    const u16* W0ih_h, const u16* W0ih_l, const u16* W0hh_h, const u16* W0hh_l,
    const float* b0, const u16* H0ph, const u16* H0pl, u16* H0nh, u16* H0nl, float* c0,
    int act1, const u16* X1h, const u16* X1l,
    const u16* W1ih_h, const u16* W1ih_l, const u16* W1hh_h, const u16* W1hh_l,
    const float* b1, const u16* H1ph, const u16* H1pl, u16* H1nh, u16* H1nl, float* c1)
{
  extern __shared__ char smem[];
  const int half = blockIdx.x >> 7;
  const int bx   = blockIdx.x & 127;
  if (half == 0 ? !act0 : !act1) return;
  lstm_body(smem, bx,
            half ? X1h : X0h, half ? X1l : X0l, half ? HH : EPAD,
            half ? W1ih_h : W0ih_h, half ? W1ih_l : W0ih_l,
            half ? W1hh_h : W0hh_h, half ? W1hh_l : W0hh_l,
            half ? b1 : b0,
            half ? H1ph : H0ph, half ? H1pl : H0pl,
            half ? H1nh : H0nh, half ? H1nl : H0nl,
            half ? c1 : c0);
}

// ---------- batched FC: out[b][p][:] = hist[p][b] @ fcW^T + fcb, all 96 steps at once ----------
__global__ __launch_bounds__(256) void fc_batch(
    const u16* __restrict__ Hh, const u16* __restrict__ Hl,   // [PP*BB][512]
    const u16* __restrict__ Wh, const u16* __restrict__ Wl,   // [384][512]
    const float* __restrict__ bfc,
    float* __restrict__ out)
{
  extern __shared__ char smem[];
  const int tid = threadIdx.x, lane = tid & 63, wid = tid >> 6;
  const int wm = wid >> 1, wn = wid & 1;
  const int m0 = blockIdx.x * 128;      // row = p*512 + b
  const int n0 = blockIdx.y * 64;

  floatx16 acc0 = {0.f,0.f,0.f,0.f,0.f,0.f,0.f,0.f,0.f,0.f,0.f,0.f,0.f,0.f,0.f,0.f};
  floatx16 acc1 = {0.f,0.f,0.f,0.f,0.f,0.f,0.f,0.f,0.f,0.f,0.f,0.f,0.f,0.f,0.f,0.f};

  const int ml    = lane & 31;
  const int thalf = lane >> 5;
  const int a0r = wm * 64 + ml;
  const int a1r = a0r + 32;
  const int brw = wn * 32 + ml;
  const int xa  = (a0r >> 1) & 3;
  const int xb  = (brw >> 1) & 3;

  const int sl  = lane & 3;
  const int rq  = lane >> 2;
  const int rx0 = wid * 32 + rq;
  const int rw  = wid * 16 + rq;
  const int sgx = (sl ^ ((rx0 >> 1) & 3)) << 4;
  const int sgw = (sl ^ ((rw  >> 1) & 3)) << 4;
  const size_t gxr0 = (size_t)(m0 + rx0);
  const size_t gxr1 = gxr0 + 16;
  const size_t gwr  = (size_t)(n0 + rw);
  const int oX = wid * 32 * 64;
  const int oW = wid * 16 * 64;

  auto stage = [&](int ch){
    const int k0 = ch << 5;
    char* b = smem + (ch & 1) * BUF_SZ;
    gload16((const char*)(Hh + gxr0 * HH + k0) + sgx, b + XH_OFF + oX);
    gload16((const char*)(Hh + gxr1 * HH + k0) + sgx, b + XH_OFF + oX + 1024);
    gload16((const char*)(Hl + gxr0 * HH + k0) + sgx, b + XL_OFF + oX);
    gload16((const char*)(Hl + gxr1 * HH + k0) + sgx, b + XL_OFF + oX + 1024);
    gload16((const char*)(Wh + gwr  * HH + k0) + sgw, b + WH_OFF + oW);
    gload16((const char*)(Wl + gwr  * HH + k0) + sgw, b + WL_OFF + oW);
  };

  stage(0);
  for (int ch = 0; ch < 16; ++ch){
    if (ch + 1 < 16) stage(ch + 1);
    __builtin_amdgcn_sched_barrier(0);
    if (ch + 1 < 16) { asm volatile("s_waitcnt vmcnt(6)" ::: "memory"); }
    else             { asm volatile("s_waitcnt vmcnt(0)" ::: "memory"); }
    __builtin_amdgcn_s_barrier();
    __builtin_amdgcn_sched_barrier(0);
    const char* bufc = smem + (ch & 1) * BUF_SZ;
    #pragma unroll
    for (int kk2 = 0; kk2 < 2; ++kk2){
      const int t0 = kk2 * 2 + thalf;
      bf16x8 ah0 = *(const bf16x8*)(bufc + XH_OFF + a0r * 64 + ((t0 ^ xa) << 4));
      bf16x8 al0 = *(const bf16x8*)(bufc + XL_OFF + a0r * 64 + ((t0 ^ xa) << 4));
      bf16x8 ah1 = *(const bf16x8*)(bufc + XH_OFF + a1r * 64 + ((t0 ^ xa) << 4));
      bf16x8 al1 = *(const bf16x8*)(bufc + XL_OFF + a1r * 64 + ((t0 ^ xa) << 4));
      bf16x8 bh  = *(const bf16x8*)(bufc + WH_OFF + brw * 64 + ((t0 ^ xb) << 4));
      bf16x8 bl  = *(const bf16x8*)(bufc + WL_OFF + brw * 64 + ((t0 ^ xb) << 4));
      acc0 = __builtin_amdgcn_mfma_f32_32x32x16_bf16(ah0, bh, acc0, 0, 0, 0);
      acc0 = __builtin_amdgcn_mfma_f32_32x32x16_bf16(ah0, bl, acc0, 0, 0, 0);
      acc0 = __builtin_amdgcn_mfma_f32_32x32x16_bf16(al0, bh, acc0, 0, 0, 0);
      acc1 = __builtin_amdgcn_mfma_f32_32x32x16_bf16(ah1, bh, acc1, 0, 0, 0);
      acc1 = __builtin_amdgcn_mfma_f32_32x32x16_bf16(ah1, bl, acc1, 0, 0, 0);
      acc1 = __builtin_amdgcn_mfma_f32_32x32x16_bf16(al1, bh, acc1, 0, 0, 0);
    }
    __builtin_amdgcn_sched_barrier(0);
    asm volatile("s_waitcnt lgkmcnt(0)" ::: "memory");
    __builtin_amdgcn_s_barrier();
    __builtin_amdgcn_sched_barrier(0);
  }

  const int n = n0 + wn * 32 + ml;
  if (n < CC){
    const float bv = bfc[n];
    #pragma unroll
    for (int r = 0; r < 16; ++r){
      const int mm = (r & 3) + 8 * (r >> 2) + 4 * thalf;
      {
        const int rr = m0 + wm * 64 + mm;              // p*512 + b
        out[(size_t)(rr & 511) * PP * CC + (size_t)(rr >> 9) * CC + n] = acc0[r] + bv;
      }
      {
        const int rr = m0 + wm * 64 + 32 + mm;
        out[(size_t)(rr & 511) * PP * CC + (size_t)(rr >> 9) * CC + n] = acc1[r] + bv;
      }
    }
  }
}

extern "C" void kernel_launch(void* const* d_in, const int* in_sizes, int n_in,
                              void* d_out, int out_size, void* d_ws, size_t ws_size,
                              hipStream_t stream) {
  const float* x_enc  = (const float*)d_in[0];
  const float* e_Wih0 = (const float*)d_in[4];
  const float* e_Whh0 = (const float*)d_in[5];
  const float* e_bih0 = (const float*)d_in[6];
  const float* e_bhh0 = (const float*)d_in[7];
  const float* e_Wih1 = (const float*)d_in[8];
  const float* e_Whh1 = (const float*)d_in[9];
  const float* e_bih1 = (const float*)d_in[10];
  const float* e_bhh1 = (const float*)d_in[11];
  const float* d_Wih0 = (const float*)d_in[12];
  const float* d_Whh0 = (const float*)d_in[13];
  const float* d_bih0 = (const float*)d_in[14];
  const float* d_bhh0 = (const float*)d_in[15];
  const float* d_Wih1 = (const float*)d_in[16];
  const float* d_Whh1 = (const float*)d_in[17];
  const float* d_bih1 = (const float*)d_in[18];
  const float* d_bhh1 = (const float*)d_in[19];
  const float* fc_W   = (const float*)d_in[20];
  const float* fc_b   = (const float*)d_in[21];

  char* base = (char*)d_ws;
  size_t off = 0;
  auto alloc_us = [&](size_t n){ u16* p = (u16*)(base + off); off += ((n * 2 + 15) & ~(size_t)15); return p; };
  auto alloc_f  = [&](size_t n){ float* p = (float*)(base + off); off += ((n * 4 + 15) & ~(size_t)15); return p; };

  u16 *We0ih_h = alloc_us((size_t)G4 * EPAD), *We0ih_l = alloc_us((size_t)G4 * EPAD);
  u16 *We0hh_h = alloc_us((size_t)G4 * HH),   *We0hh_l = alloc_us((size_t)G4 * HH);
  u16 *We1ih_h = alloc_us((size_t)G4 * HH),   *We1ih_l = alloc_us((size_t)G4 * HH);
  u16 *We1hh_h = alloc_us((size_t)G4 * HH),   *We1hh_l = alloc_us((size_t)G4 * HH);
  u16 *Wd0ih_h = alloc_us((size_t)G4 * EPAD), *Wd0ih_l = alloc_us((size_t)G4 * EPAD);
  u16 *Wd0hh_h = alloc_us((size_t)G4 * HH),   *Wd0hh_l = alloc_us((size_t)G4 * HH);
  u16 *Wd1ih_h = alloc_us((size_t)G4 * HH),   *Wd1ih_l = alloc_us((size_t)G4 * HH);
  u16 *Wd1hh_h = alloc_us((size_t)G4 * HH),   *Wd1hh_l = alloc_us((size_t)G4 * HH);
  u16 *Wfc_h   = alloc_us((size_t)NFC * HH),  *Wfc_l   = alloc_us((size_t)NFC * HH);
  u16 *Wc_h    = alloc_us((size_t)G4 * HH),   *Wc_l    = alloc_us((size_t)G4 * HH);
  float* be0 = alloc_f(G4);
  float* be1 = alloc_f(G4);
  float* bd0 = alloc_f(G4);
  float* bd1 = alloc_f(G4);
  float* bfc = alloc_f(NFC);
  float* bd0c = alloc_f(G4);
  float* Wcf32 = alloc_f((size_t)G4 * HH);
  // zero-init region: h0[0], h1[0] (hi+lo) then c0, c1 — one memset covers all
  u16* h0h[2]; u16* h0l[2]; u16* h1h[2]; u16* h1l[2];
  h0h[0] = alloc_us((size_t)BB * HH); h0l[0] = alloc_us((size_t)BB * HH);
  h1h[0] = alloc_us((size_t)BB * HH); h1l[0] = alloc_us((size_t)BB * HH);
  float* c0 = alloc_f((size_t)BB * HH);
  float* c1 = alloc_f((size_t)BB * HH);
  h0h[1] = alloc_us((size_t)BB * HH); h0l[1] = alloc_us((size_t)BB * HH);
  h1h[1] = alloc_us((size_t)BB * HH); h1l[1] = alloc_us((size_t)BB * HH);
  u16* inph = alloc_us((size_t)BB * EPAD);
  u16* inpl = alloc_us((size_t)BB * EPAD);
  u16* Xench = alloc_us((size_t)TT * BB * EPAD);
  u16* Xencl = alloc_us((size_t)TT * BB * EPAD);
  u16* histh = alloc_us((size_t)PP * BB * HH);
  u16* histl = alloc_us((size_t)PP * BB * HH);

  // prep (every launch; ws re-poisoned by harness)
  cvt_split<<<512, 256, 0, stream>>>(e_Wih0, We0ih_h, We0ih_l, G4, EE, G4, EPAD);
  cvt_split<<<512, 256, 0, stream>>>(e_Whh0, We0hh_h, We0hh_l, G4, HH, G4, HH);
  cvt_split<<<512, 256, 0, stream>>>(e_Wih1, We1ih_h, We1ih_l, G4, HH, G4, HH);
  cvt_split<<<512, 256, 0, stream>>>(e_Whh1, We1hh_h, We1hh_l, G4, HH, G4, HH);
  cvt_split<<<512, 256, 0, stream>>>(d_Wih0, Wd0ih_h, Wd0ih_l, G4, EE, G4, EPAD);
  cvt_split<<<512, 256, 0, stream>>>(d_Whh0, Wd0hh_h, Wd0hh_l, G4, HH, G4, HH);
  cvt_split<<<512, 256, 0, stream>>>(d_Wih1, Wd1ih_h, Wd1ih_l, G4, HH, G4, HH);
  cvt_split<<<512, 256, 0, stream>>>(d_Whh1, Wd1hh_h, Wd1hh_l, G4, HH, G4, HH);
  cvt_split<<<512, 256, 0, stream>>>(fc_W,   Wfc_h,   Wfc_l,   CC, HH, NFC, HH);
  cvt_bias<<<8, 256, 0, stream>>>(e_bih0, e_bhh0, be0, G4, G4);
  cvt_bias<<<8, 256, 0, stream>>>(e_bih1, e_bhh1, be1, G4, G4);
  cvt_bias<<<8, 256, 0, stream>>>(d_bih0, d_bhh0, bd0, G4, G4);
  cvt_bias<<<8, 256, 0, stream>>>(d_bih1, d_bhh1, bd1, G4, G4);
  cvt_bias<<<2, 256, 0, stream>>>(fc_b, nullptr, bfc, CC, NFC);
  // fc folding: Wcomb = Wd0ih @ fcW (fp32), bd0c = bd0 + Wd0ih @ fcb
  wcomb<<<G4, 256, 0, stream>>>(d_Wih0, fc_W, Wcf32);
  bias_fold<<<8, 256, 0, stream>>>(bd0, d_Wih0, fc_b, bd0c);
  cvt_split<<<512, 256, 0, stream>>>(Wcf32, Wc_h, Wc_l, G4, HH, G4, HH);
  hipMemsetAsync(h0h[0], 0, (size_t)4 * BB * HH * sizeof(u16) + (size_t)2 * BB * HH * sizeof(float), stream);
  init_inp<<<512, 256, 0, stream>>>(x_enc, inph, inpl);
  split_xenc<<<4096, 256, 0, stream>>>(x_enc, Xench, Xencl);

  // encoder: fused pipeline, iteration t runs cell0(t) and cell1(t-1)
  for (int t = 0; t <= TT; ++t){
    const int rd = t & 1, wrp = (t + 1) & 1;
    const size_t ts = (size_t)(t < TT ? t : 0) * BB * EPAD;
    lstm_pair<<<256, 256, LSTM_SMEM, stream>>>(
        (t < TT) ? 1 : 0, Xench + ts, Xencl + ts,
        We0ih_h, We0ih_l, We0hh_h, We0hh_l, be0,
        h0h[rd], h0l[rd], h0h[wrp], h0l[wrp], c0,
        (t > 0) ? 1 : 0, h0h[rd], h0l[rd],
        We1ih_h, We1ih_l, We1hh_h, We1hh_l, be1,
        h1h[wrp], h1l[wrp], h1h[rd], h1l[rd], c1);
  }
  // encoder finals land at parity 0 for both h0 and h1

  // decoder: 2 launches/step; fc folded into cell0 (X = h1(p-1) via Wcomb); h1 -> history slab
  const size_t S = (size_t)BB * HH;
  for (int p = 0; p < PP; ++p){
    const int rd = p & 1, wrp = (p + 1) & 1;
    const u16* hp_h = p ? histh + (size_t)(p - 1) * S : h1h[0];
    const u16* hp_l = p ? histl + (size_t)(p - 1) * S : h1l[0];
    lstm_one<<<128, 256, LSTM_SMEM, stream>>>(
        p ? hp_h : inph, p ? hp_l : inpl, p ? HH : EPAD,
        p ? Wc_h : Wd0ih_h, p ? Wc_l : Wd0ih_l, Wd0hh_h, Wd0hh_l,
        p ? bd0c : bd0,
        h0h[rd], h0l[rd], h0h[wrp], h0l[wrp], c0);
    lstm_one<<<128, 256, LSTM_SMEM, stream>>>(
        h0h[wrp], h0l[wrp], HH,
        Wd1ih_h, Wd1ih_l, Wd1hh_h, Wd1hh_l, bd1,
        hp_h, hp_l,
        histh + (size_t)p * S, histl + (size_t)p * S, c1);
  }

  // batched FC over all 96 decoder steps
  fc_batch<<<dim3((PP * BB) / 128, NFC / 64), 256, LSTM_SMEM, stream>>>(
      histh, histl, Wfc_h, Wfc_l, bfc, (float*)d_out);
}

// Round 4
// 6303.476 us; speedup vs baseline: 2.0245x; 1.2184x over previous
//
#include <hip/hip_runtime.h>
#include <hip/hip_bf16.h>

#define BB 512     // batch
#define TT 96      // encoder steps
#define PP 96      // decoder steps
#define EE 321     // input features
#define CC 321     // output channels
#define HH 512     // hidden
#define G4 2048    // 4*H
#define EPAD 352   // 321 padded to 32
#define NFC 384    // fc N pad (64-multiple)

// fc_batch (2-deep) staging: per buffer Xh[128][32] Xl[128][32] Wh[64][32] Wl[64][32] (u16)
#define BUF_SZ 24576
#define XH_OFF 0
#define XL_OFF 8192
#define WH_OFF 16384
#define WL_OFF 20480
#define FC_SMEM 49152

// lstm: 4-deep pipeline
#define SMEM128 98304   // 4 x (2*8192 + 8192)
#define SMEM64  65536   // 4 x (2*4096 + 8192)

typedef unsigned short u16;
typedef __attribute__((ext_vector_type(8))) short bf16x8;
typedef __attribute__((ext_vector_type(16))) float floatx16;

__device__ __forceinline__ void splitf(float v, u16& h, u16& l){
  __hip_bfloat16 bh = __float2bfloat16(v);
  h = *reinterpret_cast<u16*>(&bh);
  float r = v - __bfloat162float(bh);
  __hip_bfloat16 bl = __float2bfloat16(r);
  l = *reinterpret_cast<u16*>(&bl);
}

// async global->LDS, 16B per lane; LDS dest = wave-uniform base + lane*16 (linear).
__device__ __forceinline__ void gload16(const void* g, void* l){
  __builtin_amdgcn_global_load_lds((const __attribute__((address_space(1))) void*)g,
                                   (__attribute__((address_space(3))) void*)l, 16, 0, 0);
}

// ---------- prep: split fp32 [rows][cols] -> bf16 hi/lo [rowspad][colspad] ----------
__global__ void cvt_split(const float* __restrict__ src, u16* __restrict__ hi, u16* __restrict__ lo,
                          int rows, int cols, int rowspad, int colspad){
  int total = rowspad * colspad;
  for (int idx = blockIdx.x * blockDim.x + threadIdx.x; idx < total; idx += gridDim.x * blockDim.x){
    int r = idx / colspad, cc = idx - r * colspad;
    float v = (r < rows && cc < cols) ? src[(size_t)r * cols + cc] : 0.f;
    u16 h, l; splitf(v, h, l);
    hi[idx] = h; lo[idx] = l;
  }
}

__global__ void cvt_bias(const float* __restrict__ b1, const float* __restrict__ b2,
                         float* __restrict__ dst, int n, int npad){
  for (int i = blockIdx.x * blockDim.x + threadIdx.x; i < npad; i += gridDim.x * blockDim.x){
    float v = 0.f;
    if (i < n){ v = b1[i]; if (b2) v += b2[i]; }
    dst[i] = v;
  }
}

// inp split from x_enc[:, T-1, :], pad zeroed
__global__ void init_inp(const float* __restrict__ x_enc, u16* __restrict__ inph, u16* __restrict__ inpl){
  int total = BB * EPAD;
  for (int idx = blockIdx.x * blockDim.x + threadIdx.x; idx < total; idx += gridDim.x * blockDim.x){
    int b = idx / EPAD, j = idx - b * EPAD;
    float v = (j < EE) ? x_enc[(size_t)b * TT * EE + (size_t)(TT - 1) * EE + j] : 0.f;
    u16 h, l; splitf(v, h, l);
    inph[idx] = h; inpl[idx] = l;
  }
}

// pre-split x_enc [B][T][E] -> [T][B][EPAD] hi/lo
__global__ void split_xenc(const float* __restrict__ x, u16* __restrict__ xh, u16* __restrict__ xl){
  const int total = TT * BB * EPAD;
  for (int idx = blockIdx.x * blockDim.x + threadIdx.x; idx < total; idx += gridDim.x * blockDim.x){
    int e = idx % EPAD;
    int rest = idx / EPAD;
    int b = rest % BB;
    int t = rest / BB;
    float v = (e < EE) ? x[((size_t)b * TT + t) * EE + e] : 0.f;
    u16 h, l; splitf(v, h, l);
    xh[idx] = h; xl[idx] = l;
  }
}

// Wcomb[g][k] = sum_e Wd0ih[g][e] * fcW[e][k]   (fp32, one-time)
__global__ void wcomb(const float* __restrict__ A,   // [2048][321]
                      const float* __restrict__ Bm,  // [321][512]  (fc_W)
                      float* __restrict__ C){        // [2048][512]
  __shared__ float arow[EE];
  const int g = blockIdx.x;
  for (int e = threadIdx.x; e < EE; e += 256) arow[e] = A[(size_t)g * EE + e];
  __syncthreads();
  for (int k = threadIdx.x; k < HH; k += 256){
    float s = 0.f;
    for (int e = 0; e < EE; ++e) s += arow[e] * Bm[(size_t)e * HH + k];
    C[(size_t)g * HH + k] = s;
  }
}

// bd0c[g] = bd0[g] + sum_e Wd0ih[g][e] * fcb[e]
__global__ void bias_fold(const float* __restrict__ bd0, const float* __restrict__ A,
                          const float* __restrict__ fcb, float* __restrict__ out){
  int g = blockIdx.x * blockDim.x + threadIdx.x;
  if (g < G4){
    float s = bd0[g];
    for (int e = 0; e < EE; ++e) s += A[(size_t)g * EE + e] * fcb[e];
    out[g] = s;
  }
}

// ---------- LSTM cell body, templated on M-tile (128: enc full-GPU pair; 64: dec full-GPU) ----------
// tile: MT batch-rows x N=64 gate-cols (16 units x 4 gates). 256 thr = 4 waves.
// 4-deep global_load_lds pipeline, counted vmcnt (3 chunks in flight), XOR-swizzled 16B slots.
template<int MT>
__device__ __forceinline__ void lstm_body(
    char* smem, int bx,
    const u16* __restrict__ Xh, const u16* __restrict__ Xl, int K1pad,
    const u16* __restrict__ Wih_h, const u16* __restrict__ Wih_l, // [2048][K1pad]
    const u16* __restrict__ Whh_h, const u16* __restrict__ Whh_l, // [2048][512]
    const float* __restrict__ bias,
    const u16* __restrict__ Hph, const u16* __restrict__ Hpl, // prev h split [512][512]
    u16* __restrict__ Hnh, u16* __restrict__ Hnl,             // next h split
    float* __restrict__ cst)                                  // c state fp32 [512][512]
{
  constexpr int XROWB = MT * 64;           // bytes per X array per buffer
  constexpr int BUFB  = 2 * XROWB + 8192;  // Xh,Xl + Wh(4096),Wl(4096)
  constexpr int WH_O  = 2 * XROWB;
  constexpr int WL_O  = 2 * XROWB + 4096;

  float (*sG)[68] = (float (*)[68])(smem);   // aliases staging; used only after final barrier

  const int tid  = threadIdx.x;
  const int lane = tid & 63;
  const int wid  = tid >> 6;
  const int wm = wid >> 1, wn = wid & 1;
  const int m0 = (bx >> 5) * MT;
  const int u0 = (bx & 31) * 16;

  floatx16 acc0 = {0.f,0.f,0.f,0.f,0.f,0.f,0.f,0.f,0.f,0.f,0.f,0.f,0.f,0.f,0.f,0.f};
  floatx16 acc1 = acc0;   // dead (DCE'd) when MT==64

  const int ml    = lane & 31;
  const int thalf = lane >> 5;
  const int a0r = (MT == 128 ? wm * 64 : wm * 32) + ml;
  const int a1r = a0r + 32;                // MT==128 only
  const int brw = wn * 32 + ml;
  const int xa  = (a0r >> 1) & 3;          // (a1r>>1)&3 == xa (+32 rows preserves it)
  const int xb  = (brw >> 1) & 3;

  // staging: X rows = MT (wave w: rows w*(MT/4)..), W rows = 64 (wave w: rows w*16..)
  const int sl  = lane & 3;
  const int rq  = lane >> 2;               // 0..15
  const int rx0 = wid * (MT / 4) + rq;
  const int rw  = wid * 16 + rq;
  const int sgx = (sl ^ ((rx0 >> 1) & 3)) << 4;   // same swizzle valid for rows rx0+16
  const int sgw = (sl ^ ((rw  >> 1) & 3)) << 4;
  const size_t gxr0 = (size_t)(m0 + rx0);
  const size_t gxr1 = gxr0 + 16;                  // MT==128 only
  const size_t gwr  = (size_t)wid * HH + u0 + rq; // gate-row remap
  const int oX = wid * (MT / 4) * 64;
  const int oW = wid * 16 * 64;

  const int nch1 = K1pad >> 5;
  const int ncht = nch1 + (HH >> 5);       // >= 27 always

  auto stage = [&](int ch){
    const bool p1 = ch < nch1;
    const int k0 = (p1 ? ch : ch - nch1) << 5;
    const u16* xh = p1 ? Xh : Hph;
    const u16* xl = p1 ? Xl : Hpl;
    const u16* wh = p1 ? Wih_h : Whh_h;
    const u16* wl = p1 ? Wih_l : Whh_l;
    const size_t Kp = p1 ? (size_t)K1pad : (size_t)HH;
    char* b = smem + (ch & 3) * BUFB;
    gload16((const char*)(xh + gxr0 * Kp + k0) + sgx, b + oX);
    if constexpr (MT == 128) gload16((const char*)(xh + gxr1 * Kp + k0) + sgx, b + oX + 1024);
    gload16((const char*)(xl + gxr0 * Kp + k0) + sgx, b + XROWB + oX);
    if constexpr (MT == 128) gload16((const char*)(xl + gxr1 * Kp + k0) + sgx, b + XROWB + oX + 1024);
    gload16((const char*)(wh + gwr  * Kp + k0) + sgw, b + WH_O + oW);
    gload16((const char*)(wl + gwr  * Kp + k0) + sgw, b + WL_O + oW);
  };

  // prologue: 3 chunks in flight
  stage(0); stage(1); stage(2);
  for (int ch = 0; ch < ncht; ++ch){
    if (ch + 3 < ncht) stage(ch + 3);
    __builtin_amdgcn_sched_barrier(0);
    const int rem = ncht - 1 - ch;         // newer chunks still in flight after this wait
    if constexpr (MT == 128){
      if      (rem >= 3) asm volatile("s_waitcnt vmcnt(18)" ::: "memory");
      else if (rem == 2) asm volatile("s_waitcnt vmcnt(12)" ::: "memory");
      else if (rem == 1) asm volatile("s_waitcnt vmcnt(6)"  ::: "memory");
      else               asm volatile("s_waitcnt vmcnt(0)"  ::: "memory");
    } else {
      if      (rem >= 3) asm volatile("s_waitcnt vmcnt(12)" ::: "memory");
      else if (rem == 2) asm volatile("s_waitcnt vmcnt(8)"  ::: "memory");
      else if (rem == 1) asm volatile("s_waitcnt vmcnt(4)"  ::: "memory");
      else               asm volatile("s_waitcnt vmcnt(0)"  ::: "memory");
    }
    __builtin_amdgcn_s_barrier();          // all waves: chunk ch resident
    __builtin_amdgcn_sched_barrier(0);
    const char* bufc = smem + (ch & 3) * BUFB;
    #pragma unroll
    for (int kk2 = 0; kk2 < 2; ++kk2){
      const int t0 = kk2 * 2 + thalf;
      bf16x8 ah0 = *(const bf16x8*)(bufc + a0r * 64 + ((t0 ^ xa) << 4));
      bf16x8 al0 = *(const bf16x8*)(bufc + XROWB + a0r * 64 + ((t0 ^ xa) << 4));
      bf16x8 bh  = *(const bf16x8*)(bufc + WH_O + brw * 64 + ((t0 ^ xb) << 4));
      bf16x8 bl  = *(const bf16x8*)(bufc + WL_O + brw * 64 + ((t0 ^ xb) << 4));
      acc0 = __builtin_amdgcn_mfma_f32_32x32x16_bf16(ah0, bh, acc0, 0, 0, 0);
      acc0 = __builtin_amdgcn_mfma_f32_32x32x16_bf16(ah0, bl, acc0, 0, 0, 0);
      acc0 = __builtin_amdgcn_mfma_f32_32x32x16_bf16(al0, bh, acc0, 0, 0, 0);
      if constexpr (MT == 128){
        bf16x8 ah1 = *(const bf16x8*)(bufc + a1r * 64 + ((t0 ^ xa) << 4));
        bf16x8 al1 = *(const bf16x8*)(bufc + XROWB + a1r * 64 + ((t0 ^ xa) << 4));
        acc1 = __builtin_amdgcn_mfma_f32_32x32x16_bf16(ah1, bh, acc1, 0, 0, 0);
        acc1 = __builtin_amdgcn_mfma_f32_32x32x16_bf16(ah1, bl, acc1, 0, 0, 0);
        acc1 = __builtin_amdgcn_mfma_f32_32x32x16_bf16(al1, bh, acc1, 0, 0, 0);
      }
    }
    __builtin_amdgcn_sched_barrier(0);
    asm volatile("s_waitcnt lgkmcnt(0)" ::: "memory");
    __builtin_amdgcn_s_barrier();          // all waves done reading buffer (ch&3) before reuse
    __builtin_amdgcn_sched_barrier(0);
  }
  __syncthreads();  // fence before sG aliases the staging buffers

  // ---- epilogue: gate exchange via LDS (aliased), cell update, split-write h ----
  #pragma unroll
  for (int r = 0; r < 16; ++r){
    const int mm = (r & 3) + 8 * (r >> 2) + 4 * thalf;
    if constexpr (MT == 128){
      sG[wm * 64 + mm][wn * 32 + ml]      = acc0[r];
      sG[wm * 64 + 32 + mm][wn * 32 + ml] = acc1[r];
    } else {
      sG[wm * 32 + mm][wn * 32 + ml]      = acc0[r];
    }
  }
  __syncthreads();
  for (int e = tid; e < MT * 16; e += 256){
    const int m = e >> 4, u = e & 15;
    const int gj = u0 + u;
    const float gi = sG[m][u]      + bias[gj];
    const float gf = sG[m][16 + u] + bias[HH + gj];
    const float gg = sG[m][32 + u] + bias[2 * HH + gj];
    const float go = sG[m][48 + u] + bias[3 * HH + gj];
    const float si = 1.f / (1.f + expf(-gi));
    const float sf = 1.f / (1.f + expf(-gf));
    const float so = 1.f / (1.f + expf(-go));
    const size_t sidx = (size_t)(m0 + m) * HH + gj;
    const float cn = sf * cst[sidx] + si * tanhf(gg);
    const float hn = so * tanhf(cn);
    cst[sidx] = cn;
    u16 hh, hl; splitf(hn, hh, hl);
    Hnh[sidx] = hh; Hnl[sidx] = hl;
  }
}

// decoder cell: M=64 tiles -> 256 blocks (full GPU)
__global__ __launch_bounds__(256) void lstm_one(
    const u16* Xh, const u16* Xl, int K1pad,
    const u16* Wih_h, const u16* Wih_l, const u16* Whh_h, const u16* Whh_l,
    const float* bias, const u16* Hph, const u16* Hpl,
    u16* Hnh, u16* Hnl, float* cst)
{
  extern __shared__ char smem[];
  lstm_body<64>(smem, blockIdx.x, Xh, Xl, K1pad,
                Wih_h, Wih_l, Whh_h, Whh_l, bias, Hph, Hpl, Hnh, Hnl, cst);
}

// Fused encoder step: blocks [0,128) = cell0(t), [128,256) = cell1(t-1). M=128 tiles.
__global__ __launch_bounds__(256) void lstm_pair(
    int act0, const u16* X0h, const u16* X0l,
    const u16* W0ih_h, const u16* W0ih_l, const u16* W0hh_h, const u16* W0hh_l,
    const float* b0, const u16* H0ph, const u16* H0pl, u16* H0nh, u16* H0nl, float* c0,
    int act1, const u16* X1h, const u16* X1l,
    const u16* W1ih_h, const u16* W1ih_l, const u16* W1hh_h, const u16* W1hh_l,
    const float* b1, const u16* H1ph, const u16* H1pl, u16* H1nh, u16* H1nl, float* c1)
{
  extern __shared__ char smem[];
  const int half = blockIdx.x >> 7;
  const int bx   = blockIdx.x & 127;
  if (half == 0 ? !act0 : !act1) return;
  lstm_body<128>(smem, bx,
                 half ? X1h : X0h, half ? X1l : X0l, half ? HH : EPAD,
                 half ? W1ih_h : W0ih_h, half ? W1ih_l : W0ih_l,
                 half ? W1hh_h : W0hh_h, half ? W1hh_l : W0hh_l,
                 half ? b1 : b0,
                 half ? H1ph : H0ph, half ? H1pl : H0pl,
                 half ? H1nh : H0nh, half ? H1nl : H0nl,
                 half ? c1 : c0);
}

// ---------- batched FC: out[b][p][:] = hist[p][b] @ fcW^T + fcb, all 96 steps at once ----------
__global__ __launch_bounds__(256) void fc_batch(
    const u16* __restrict__ Hh, const u16* __restrict__ Hl,   // [PP*BB][512]
    const u16* __restrict__ Wh, const u16* __restrict__ Wl,   // [384][512]
    const float* __restrict__ bfc,
    float* __restrict__ out)
{
  extern __shared__ char smem[];
  const int tid = threadIdx.x, lane = tid & 63, wid = tid >> 6;
  const int wm = wid >> 1, wn = wid & 1;
  const int m0 = blockIdx.x * 128;      // row = p*512 + b
  const int n0 = blockIdx.y * 64;

  floatx16 acc0 = {0.f,0.f,0.f,0.f,0.f,0.f,0.f,0.f,0.f,0.f,0.f,0.f,0.f,0.f,0.f,0.f};
  floatx16 acc1 = {0.f,0.f,0.f,0.f,0.f,0.f,0.f,0.f,0.f,0.f,0.f,0.f,0.f,0.f,0.f,0.f};

  const int ml    = lane & 31;
  const int thalf = lane >> 5;
  const int a0r = wm * 64 + ml;
  const int a1r = a0r + 32;
  const int brw = wn * 32 + ml;
  const int xa  = (a0r >> 1) & 3;
  const int xb  = (brw >> 1) & 3;

  const int sl  = lane & 3;
  const int rq  = lane >> 2;
  const int rx0 = wid * 32 + rq;
  const int rw  = wid * 16 + rq;
  const int sgx = (sl ^ ((rx0 >> 1) & 3)) << 4;
  const int sgw = (sl ^ ((rw  >> 1) & 3)) << 4;
  const size_t gxr0 = (size_t)(m0 + rx0);
  const size_t gxr1 = gxr0 + 16;
  const size_t gwr  = (size_t)(n0 + rw);
  const int oX = wid * 32 * 64;
  const int oW = wid * 16 * 64;

  auto stage = [&](int ch){
    const int k0 = ch << 5;
    char* b = smem + (ch & 1) * BUF_SZ;
    gload16((const char*)(Hh + gxr0 * HH + k0) + sgx, b + XH_OFF + oX);
    gload16((const char*)(Hh + gxr1 * HH + k0) + sgx, b + XH_OFF + oX + 1024);
    gload16((const char*)(Hl + gxr0 * HH + k0) + sgx, b + XL_OFF + oX);
    gload16((const char*)(Hl + gxr1 * HH + k0) + sgx, b + XL_OFF + oX + 1024);
    gload16((const char*)(Wh + gwr  * HH + k0) + sgw, b + WH_OFF + oW);
    gload16((const char*)(Wl + gwr  * HH + k0) + sgw, b + WL_OFF + oW);
  };

  stage(0);
  for (int ch = 0; ch < 16; ++ch){
    if (ch + 1 < 16) stage(ch + 1);
    __builtin_amdgcn_sched_barrier(0);
    if (ch + 1 < 16) { asm volatile("s_waitcnt vmcnt(6)" ::: "memory"); }
    else             { asm volatile("s_waitcnt vmcnt(0)" ::: "memory"); }
    __builtin_amdgcn_s_barrier();
    __builtin_amdgcn_sched_barrier(0);
    const char* bufc = smem + (ch & 1) * BUF_SZ;
    #pragma unroll
    for (int kk2 = 0; kk2 < 2; ++kk2){
      const int t0 = kk2 * 2 + thalf;
      bf16x8 ah0 = *(const bf16x8*)(bufc + XH_OFF + a0r * 64 + ((t0 ^ xa) << 4));
      bf16x8 al0 = *(const bf16x8*)(bufc + XL_OFF + a0r * 64 + ((t0 ^ xa) << 4));
      bf16x8 ah1 = *(const bf16x8*)(bufc + XH_OFF + a1r * 64 + ((t0 ^ xa) << 4));
      bf16x8 al1 = *(const bf16x8*)(bufc + XL_OFF + a1r * 64 + ((t0 ^ xa) << 4));
      bf16x8 bh  = *(const bf16x8*)(bufc + WH_OFF + brw * 64 + ((t0 ^ xb) << 4));
      bf16x8 bl  = *(const bf16x8*)(bufc + WL_OFF + brw * 64 + ((t0 ^ xb) << 4));
      acc0 = __builtin_amdgcn_mfma_f32_32x32x16_bf16(ah0, bh, acc0, 0, 0, 0);
      acc0 = __builtin_amdgcn_mfma_f32_32x32x16_bf16(ah0, bl, acc0, 0, 0, 0);
      acc0 = __builtin_amdgcn_mfma_f32_32x32x16_bf16(al0, bh, acc0, 0, 0, 0);
      acc1 = __builtin_amdgcn_mfma_f32_32x32x16_bf16(ah1, bh, acc1, 0, 0, 0);
      acc1 = __builtin_amdgcn_mfma_f32_32x32x16_bf16(ah1, bl, acc1, 0, 0, 0);
      acc1 = __builtin_amdgcn_mfma_f32_32x32x16_bf16(al1, bh, acc1, 0, 0, 0);
    }
    __builtin_amdgcn_sched_barrier(0);
    asm volatile("s_waitcnt lgkmcnt(0)" ::: "memory");
    __builtin_amdgcn_s_barrier();
    __builtin_amdgcn_sched_barrier(0);
  }

  const int n = n0 + wn * 32 + ml;
  if (n < CC){
    const float bv = bfc[n];
    #pragma unroll
    for (int r = 0; r < 16; ++r){
      const int mm = (r & 3) + 8 * (r >> 2) + 4 * thalf;
      {
        const int rr = m0 + wm * 64 + mm;              // p*512 + b
        out[(size_t)(rr & 511) * PP * CC + (size_t)(rr >> 9) * CC + n] = acc0[r] + bv;
      }
      {
        const int rr = m0 + wm * 64 + 32 + mm;
        out[(size_t)(rr & 511) * PP * CC + (size_t)(rr >> 9) * CC + n] = acc1[r] + bv;
      }
    }
  }
}

extern "C" void kernel_launch(void* const* d_in, const int* in_sizes, int n_in,
                              void* d_out, int out_size, void* d_ws, size_t ws_size,
                              hipStream_t stream) {
  const float* x_enc  = (const float*)d_in[0];
  const float* e_Wih0 = (const float*)d_in[4];
  const float* e_Whh0 = (const float*)d_in[5];
  const float* e_bih0 = (const float*)d_in[6];
  const float* e_bhh0 = (const float*)d_in[7];
  const float* e_Wih1 = (const float*)d_in[8];
  const float* e_Whh1 = (const float*)d_in[9];
  const float* e_bih1 = (const float*)d_in[10];
  const float* e_bhh1 = (const float*)d_in[11];
  const float* d_Wih0 = (const float*)d_in[12];
  const float* d_Whh0 = (const float*)d_in[13];
  const float* d_bih0 = (const float*)d_in[14];
  const float* d_bhh0 = (const float*)d_in[15];
  const float* d_Wih1 = (const float*)d_in[16];
  const float* d_Whh1 = (const float*)d_in[17];
  const float* d_bih1 = (const float*)d_in[18];
  const float* d_bhh1 = (const float*)d_in[19];
  const float* fc_W   = (const float*)d_in[20];
  const float* fc_b   = (const float*)d_in[21];

  // allow >64KB dynamic LDS for the 4-deep encoder pipeline (idempotent, host-side, capture-safe)
  static bool attr_done = false;
  if (!attr_done){
    hipFuncSetAttribute((const void*)lstm_pair, hipFuncAttributeMaxDynamicSharedMemorySize, SMEM128);
    hipFuncSetAttribute((const void*)lstm_one,  hipFuncAttributeMaxDynamicSharedMemorySize, SMEM64);
    attr_done = true;
  }

  char* base = (char*)d_ws;
  size_t off = 0;
  auto alloc_us = [&](size_t n){ u16* p = (u16*)(base + off); off += ((n * 2 + 15) & ~(size_t)15); return p; };
  auto alloc_f  = [&](size_t n){ float* p = (float*)(base + off); off += ((n * 4 + 15) & ~(size_t)15); return p; };

  u16 *We0ih_h = alloc_us((size_t)G4 * EPAD), *We0ih_l = alloc_us((size_t)G4 * EPAD);
  u16 *We0hh_h = alloc_us((size_t)G4 * HH),   *We0hh_l = alloc_us((size_t)G4 * HH);
  u16 *We1ih_h = alloc_us((size_t)G4 * HH),   *We1ih_l = alloc_us((size_t)G4 * HH);
  u16 *We1hh_h = alloc_us((size_t)G4 * HH),   *We1hh_l = alloc_us((size_t)G4 * HH);
  u16 *Wd0ih_h = alloc_us((size_t)G4 * EPAD), *Wd0ih_l = alloc_us((size_t)G4 * EPAD);
  u16 *Wd0hh_h = alloc_us((size_t)G4 * HH),   *Wd0hh_l = alloc_us((size_t)G4 * HH);
  u16 *Wd1ih_h = alloc_us((size_t)G4 * HH),   *Wd1ih_l = alloc_us((size_t)G4 * HH);
  u16 *Wd1hh_h = alloc_us((size_t)G4 * HH),   *Wd1hh_l = alloc_us((size_t)G4 * HH);
  u16 *Wfc_h   = alloc_us((size_t)NFC * HH),  *Wfc_l   = alloc_us((size_t)NFC * HH);
  u16 *Wc_h    = alloc_us((size_t)G4 * HH),   *Wc_l    = alloc_us((size_t)G4 * HH);
  float* be0 = alloc_f(G4);
  float* be1 = alloc_f(G4);
  float* bd0 = alloc_f(G4);
  float* bd1 = alloc_f(G4);
  float* bfc = alloc_f(NFC);
  float* bd0c = alloc_f(G4);
  float* Wcf32 = alloc_f((size_t)G4 * HH);
  // zero-init region: h0[0], h1[0] (hi+lo) then c0, c1 — one memset covers all
  u16* h0h[2]; u16* h0l[2]; u16* h1h[2]; u16* h1l[2];
  h0h[0] = alloc_us((size_t)BB * HH); h0l[0] = alloc_us((size_t)BB * HH);
  h1h[0] = alloc_us((size_t)BB * HH); h1l[0] = alloc_us((size_t)BB * HH);
  float* c0 = alloc_f((size_t)BB * HH);
  float* c1 = alloc_f((size_t)BB * HH);
  h0h[1] = alloc_us((size_t)BB * HH); h0l[1] = alloc_us((size_t)BB * HH);
  h1h[1] = alloc_us((size_t)BB * HH); h1l[1] = alloc_us((size_t)BB * HH);
  u16* inph = alloc_us((size_t)BB * EPAD);
  u16* inpl = alloc_us((size_t)BB * EPAD);
  u16* Xench = alloc_us((size_t)TT * BB * EPAD);
  u16* Xencl = alloc_us((size_t)TT * BB * EPAD);
  u16* histh = alloc_us((size_t)PP * BB * HH);
  u16* histl = alloc_us((size_t)PP * BB * HH);

  // prep (every launch; ws re-poisoned by harness)
  cvt_split<<<512, 256, 0, stream>>>(e_Wih0, We0ih_h, We0ih_l, G4, EE, G4, EPAD);
  cvt_split<<<512, 256, 0, stream>>>(e_Whh0, We0hh_h, We0hh_l, G4, HH, G4, HH);
  cvt_split<<<512, 256, 0, stream>>>(e_Wih1, We1ih_h, We1ih_l, G4, HH, G4, HH);
  cvt_split<<<512, 256, 0, stream>>>(e_Whh1, We1hh_h, We1hh_l, G4, HH, G4, HH);
  cvt_split<<<512, 256, 0, stream>>>(d_Wih0, Wd0ih_h, Wd0ih_l, G4, EE, G4, EPAD);
  cvt_split<<<512, 256, 0, stream>>>(d_Whh0, Wd0hh_h, Wd0hh_l, G4, HH, G4, HH);
  cvt_split<<<512, 256, 0, stream>>>(d_Wih1, Wd1ih_h, Wd1ih_l, G4, HH, G4, HH);
  cvt_split<<<512, 256, 0, stream>>>(d_Whh1, Wd1hh_h, Wd1hh_l, G4, HH, G4, HH);
  cvt_split<<<512, 256, 0, stream>>>(fc_W,   Wfc_h,   Wfc_l,   CC, HH, NFC, HH);
  cvt_bias<<<8, 256, 0, stream>>>(e_bih0, e_bhh0, be0, G4, G4);
  cvt_bias<<<8, 256, 0, stream>>>(e_bih1, e_bhh1, be1, G4, G4);
  cvt_bias<<<8, 256, 0, stream>>>(d_bih0, d_bhh0, bd0, G4, G4);
  cvt_bias<<<8, 256, 0, stream>>>(d_bih1, d_bhh1, bd1, G4, G4);
  cvt_bias<<<2, 256, 0, stream>>>(fc_b, nullptr, bfc, CC, NFC);
  // fc folding: Wcomb = Wd0ih @ fcW (fp32), bd0c = bd0 + Wd0ih @ fcb
  wcomb<<<G4, 256, 0, stream>>>(d_Wih0, fc_W, Wcf32);
  bias_fold<<<8, 256, 0, stream>>>(bd0, d_Wih0, fc_b, bd0c);
  cvt_split<<<512, 256, 0, stream>>>(Wcf32, Wc_h, Wc_l, G4, HH, G4, HH);
  hipMemsetAsync(h0h[0], 0, (size_t)4 * BB * HH * sizeof(u16) + (size_t)2 * BB * HH * sizeof(float), stream);
  init_inp<<<512, 256, 0, stream>>>(x_enc, inph, inpl);
  split_xenc<<<4096, 256, 0, stream>>>(x_enc, Xench, Xencl);

  // encoder: fused pipeline, iteration t runs cell0(t) and cell1(t-1)
  for (int t = 0; t <= TT; ++t){
    const int rd = t & 1, wrp = (t + 1) & 1;
    const size_t ts = (size_t)(t < TT ? t : 0) * BB * EPAD;
    lstm_pair<<<256, 256, SMEM128, stream>>>(
        (t < TT) ? 1 : 0, Xench + ts, Xencl + ts,
        We0ih_h, We0ih_l, We0hh_h, We0hh_l, be0,
        h0h[rd], h0l[rd], h0h[wrp], h0l[wrp], c0,
        (t > 0) ? 1 : 0, h0h[rd], h0l[rd],
        We1ih_h, We1ih_l, We1hh_h, We1hh_l, be1,
        h1h[wrp], h1l[wrp], h1h[rd], h1l[rd], c1);
  }
  // encoder finals land at parity 0 for both h0 and h1

  // decoder: 2 full-GPU launches/step (M=64 tiles); fc folded into cell0 via Wcomb
  const size_t S = (size_t)BB * HH;
  for (int p = 0; p < PP; ++p){
    const int rd = p & 1, wrp = (p + 1) & 1;
    const u16* hp_h = p ? histh + (size_t)(p - 1) * S : h1h[0];
    const u16* hp_l = p ? histl + (size_t)(p - 1) * S : h1l[0];
    lstm_one<<<256, 256, SMEM64, stream>>>(
        p ? hp_h : inph, p ? hp_l : inpl, p ? HH : EPAD,
        p ? Wc_h : Wd0ih_h, p ? Wc_l : Wd0ih_l, Wd0hh_h, Wd0hh_l,
        p ? bd0c : bd0,
        h0h[rd], h0l[rd], h0h[wrp], h0l[wrp], c0);
    lstm_one<<<256, 256, SMEM64, stream>>>(
        h0h[wrp], h0l[wrp], HH,
        Wd1ih_h, Wd1ih_l, Wd1hh_h, Wd1hh_l, bd1,
        hp_h, hp_l,
        histh + (size_t)p * S, histl + (size_t)p * S, c1);
  }

  // batched FC over all 96 decoder steps
  fc_batch<<<dim3((PP * BB) / 128, NFC / 64), 256, FC_SMEM, stream>>>(
      histh, histl, Wfc_h, Wfc_l, bfc, (float*)d_out);
}

// Round 5
// 5868.959 us; speedup vs baseline: 2.1744x; 1.0740x over previous
//
#include <hip/hip_runtime.h>
#include <hip/hip_bf16.h>

#define BB 512     // batch
#define TT 96      // encoder steps
#define PP 96      // decoder steps
#define EE 321     // input features
#define CC 321     // output channels
#define HH 512     // hidden
#define G4 2048    // 4*H
#define EPAD 352   // 321 padded to 32
#define NFC 384    // fc N pad (64-multiple)

// fc_batch (2-deep) staging
#define BUF_SZ 24576
#define XH_OFF 0
#define XL_OFF 8192
#define WH_OFF 16384
#define WL_OFF 20480
#define FC_SMEM 49152

// lstm: 4-deep pipeline
#define SMEM128 98304   // 4 x (2*8192 + 8192)  (encoder pair, M=128)
#define DEC_SMEM 65536  // 4 x (2*4096 + 8192)  (decoder M=64; 2 blocks/CU)

typedef unsigned short u16;
typedef __attribute__((ext_vector_type(8))) short bf16x8;
typedef __attribute__((ext_vector_type(16))) float floatx16;

__device__ __forceinline__ void splitf(float v, u16& h, u16& l){
  __hip_bfloat16 bh = __float2bfloat16(v);
  h = *reinterpret_cast<u16*>(&bh);
  float r = v - __bfloat162float(bh);
  __hip_bfloat16 bl = __float2bfloat16(r);
  l = *reinterpret_cast<u16*>(&bl);
}

// async global->LDS, 16B per lane; LDS dest = wave-uniform base + lane*16 (linear).
__device__ __forceinline__ void gload16(const void* g, void* l){
  __builtin_amdgcn_global_load_lds((const __attribute__((address_space(1))) void*)g,
                                   (__attribute__((address_space(3))) void*)l, 16, 0, 0);
}

// ---------- prep kernels ----------
__global__ void cvt_split(const float* __restrict__ src, u16* __restrict__ hi, u16* __restrict__ lo,
                          int rows, int cols, int rowspad, int colspad){
  int total = rowspad * colspad;
  for (int idx = blockIdx.x * blockDim.x + threadIdx.x; idx < total; idx += gridDim.x * blockDim.x){
    int r = idx / colspad, cc = idx - r * colspad;
    float v = (r < rows && cc < cols) ? src[(size_t)r * cols + cc] : 0.f;
    u16 h, l; splitf(v, h, l);
    hi[idx] = h; lo[idx] = l;
  }
}

__global__ void cvt_bias(const float* __restrict__ b1, const float* __restrict__ b2,
                         float* __restrict__ dst, int n, int npad){
  for (int i = blockIdx.x * blockDim.x + threadIdx.x; i < npad; i += gridDim.x * blockDim.x){
    float v = 0.f;
    if (i < n){ v = b1[i]; if (b2) v += b2[i]; }
    dst[i] = v;
  }
}

__global__ void init_inp(const float* __restrict__ x_enc, u16* __restrict__ inph, u16* __restrict__ inpl){
  int total = BB * EPAD;
  for (int idx = blockIdx.x * blockDim.x + threadIdx.x; idx < total; idx += gridDim.x * blockDim.x){
    int b = idx / EPAD, j = idx - b * EPAD;
    float v = (j < EE) ? x_enc[(size_t)b * TT * EE + (size_t)(TT - 1) * EE + j] : 0.f;
    u16 h, l; splitf(v, h, l);
    inph[idx] = h; inpl[idx] = l;
  }
}

__global__ void split_xenc(const float* __restrict__ x, u16* __restrict__ xh, u16* __restrict__ xl){
  const int total = TT * BB * EPAD;
  for (int idx = blockIdx.x * blockDim.x + threadIdx.x; idx < total; idx += gridDim.x * blockDim.x){
    int e = idx % EPAD;
    int rest = idx / EPAD;
    int b = rest % BB;
    int t = rest / BB;
    float v = (e < EE) ? x[((size_t)b * TT + t) * EE + e] : 0.f;
    u16 h, l; splitf(v, h, l);
    xh[idx] = h; xl[idx] = l;
  }
}

// Wcomb[g][k] = sum_e Wd0ih[g][e] * fcW[e][k]   (fp32, one-time)
__global__ void wcomb(const float* __restrict__ A, const float* __restrict__ Bm,
                      float* __restrict__ C){
  __shared__ float arow[EE];
  const int g = blockIdx.x;
  for (int e = threadIdx.x; e < EE; e += 256) arow[e] = A[(size_t)g * EE + e];
  __syncthreads();
  for (int k = threadIdx.x; k < HH; k += 256){
    float s = 0.f;
    for (int e = 0; e < EE; ++e) s += arow[e] * Bm[(size_t)e * HH + k];
    C[(size_t)g * HH + k] = s;
  }
}

__global__ void bias_fold(const float* __restrict__ bd0, const float* __restrict__ A,
                          const float* __restrict__ fcb, float* __restrict__ out){
  int g = blockIdx.x * blockDim.x + threadIdx.x;
  if (g < G4){
    float s = bd0[g];
    for (int e = 0; e < EE; ++e) s += A[(size_t)g * EE + e] * fcb[e];
    out[g] = s;
  }
}

// ---------- LSTM cell body ----------
// MT batch-rows x N=64 gate-cols. 4 waves. 4-deep gload_lds pipeline, counted vmcnt,
// ONE barrier per chunk: {vmcnt; lgkmcnt(0); barrier; stage(ch+3); reads+MFMA}.
// Safety: wave A past barrier(ch) => all waves executed lgkmcnt(0) => chunk ch-1 reads
// retired before stage(ch+3) overwrites buffer (ch-1)&3.
// Hph==null => single-phase K (no Whh). Gin!=null => add precomputed partial gates.
template<int MT>
__device__ __forceinline__ void lstm_body(
    char* smem, int bx,
    const u16* __restrict__ Xh, const u16* __restrict__ Xl, int K1pad,
    const u16* __restrict__ Wih_h, const u16* __restrict__ Wih_l,
    const u16* __restrict__ Whh_h, const u16* __restrict__ Whh_l,
    const float* __restrict__ bias, const float* __restrict__ Gin,
    const u16* __restrict__ Hph, const u16* __restrict__ Hpl,
    u16* __restrict__ Hnh, u16* __restrict__ Hnl,
    float* __restrict__ cst)
{
  constexpr int XROWB = MT * 64;
  constexpr int BUFB  = 2 * XROWB + 8192;
  constexpr int WH_O  = 2 * XROWB;
  constexpr int WL_O  = 2 * XROWB + 4096;

  float (*sG)[68] = (float (*)[68])(smem);   // aliases staging; used only after final syncthreads

  const int tid  = threadIdx.x;
  const int lane = tid & 63;
  const int wid  = tid >> 6;
  const int wm = wid >> 1, wn = wid & 1;
  const int m0 = (bx >> 5) * MT;
  const int u0 = (bx & 31) * 16;

  floatx16 acc0 = {0.f,0.f,0.f,0.f,0.f,0.f,0.f,0.f,0.f,0.f,0.f,0.f,0.f,0.f,0.f,0.f};
  floatx16 acc1 = acc0;   // dead (DCE'd) when MT==64

  const int ml    = lane & 31;
  const int thalf = lane >> 5;
  const int a0r = (MT == 128 ? wm * 64 : wm * 32) + ml;
  const int a1r = a0r + 32;                // MT==128 only
  const int brw = wn * 32 + ml;
  const int xa  = (a0r >> 1) & 3;
  const int xb  = (brw >> 1) & 3;

  const int sl  = lane & 3;
  const int rq  = lane >> 2;
  const int rx0 = wid * (MT / 4) + rq;
  const int rw  = wid * 16 + rq;
  const int sgx = (sl ^ ((rx0 >> 1) & 3)) << 4;
  const int sgw = (sl ^ ((rw  >> 1) & 3)) << 4;
  const size_t gxr0 = (size_t)(m0 + rx0);
  const size_t gxr1 = gxr0 + 16;                  // MT==128 only
  const size_t gwr  = (size_t)wid * HH + u0 + rq; // gate-row remap
  const int oX = wid * (MT / 4) * 64;
  const int oW = wid * 16 * 64;

  const int nch1 = K1pad >> 5;
  const int ncht = Hph ? nch1 + (HH >> 5) : nch1;  // >= 11 always

  auto stage = [&](int ch){
    const bool p1 = ch < nch1;
    const int k0 = (p1 ? ch : ch - nch1) << 5;
    const u16* xh = p1 ? Xh : Hph;
    const u16* xl = p1 ? Xl : Hpl;
    const u16* wh = p1 ? Wih_h : Whh_h;
    const u16* wl = p1 ? Wih_l : Whh_l;
    const size_t Kp = p1 ? (size_t)K1pad : (size_t)HH;
    char* b = smem + (ch & 3) * BUFB;
    gload16((const char*)(xh + gxr0 * Kp + k0) + sgx, b + oX);
    if constexpr (MT == 128) gload16((const char*)(xh + gxr1 * Kp + k0) + sgx, b + oX + 1024);
    gload16((const char*)(xl + gxr0 * Kp + k0) + sgx, b + XROWB + oX);
    if constexpr (MT == 128) gload16((const char*)(xl + gxr1 * Kp + k0) + sgx, b + XROWB + oX + 1024);
    gload16((const char*)(wh + gwr  * Kp + k0) + sgw, b + WH_O + oW);
    gload16((const char*)(wl + gwr  * Kp + k0) + sgw, b + WL_O + oW);
  };

  // prologue: 3 chunks in flight (ncht >= 11 always)
  stage(0); stage(1); stage(2);
  for (int ch = 0; ch < ncht; ++ch){
    const int rem = (ncht - 1 - ch) < 2 ? (ncht - 1 - ch) : 2;  // newer chunks in flight
    __builtin_amdgcn_sched_barrier(0);
    if constexpr (MT == 128){
      if      (rem == 2) asm volatile("s_waitcnt vmcnt(12)" ::: "memory");
      else if (rem == 1) asm volatile("s_waitcnt vmcnt(6)"  ::: "memory");
      else               asm volatile("s_waitcnt vmcnt(0)"  ::: "memory");
    } else {
      if      (rem == 2) asm volatile("s_waitcnt vmcnt(8)"  ::: "memory");
      else if (rem == 1) asm volatile("s_waitcnt vmcnt(4)"  ::: "memory");
      else               asm volatile("s_waitcnt vmcnt(0)"  ::: "memory");
    }
    asm volatile("s_waitcnt lgkmcnt(0)" ::: "memory");   // my ch-1 reads retired
    __builtin_amdgcn_s_barrier();                        // chunk ch resident; ch-1 reads globally done
    __builtin_amdgcn_sched_barrier(0);
    if (ch + 3 < ncht) stage(ch + 3);                    // writes buf (ch-1)&3: safe now
    const char* bufc = smem + (ch & 3) * BUFB;
    #pragma unroll
    for (int kk2 = 0; kk2 < 2; ++kk2){
      const int t0 = kk2 * 2 + thalf;
      bf16x8 ah0 = *(const bf16x8*)(bufc + a0r * 64 + ((t0 ^ xa) << 4));
      bf16x8 al0 = *(const bf16x8*)(bufc + XROWB + a0r * 64 + ((t0 ^ xa) << 4));
      bf16x8 bh  = *(const bf16x8*)(bufc + WH_O + brw * 64 + ((t0 ^ xb) << 4));
      bf16x8 bl  = *(const bf16x8*)(bufc + WL_O + brw * 64 + ((t0 ^ xb) << 4));
      acc0 = __builtin_amdgcn_mfma_f32_32x32x16_bf16(ah0, bh, acc0, 0, 0, 0);
      acc0 = __builtin_amdgcn_mfma_f32_32x32x16_bf16(ah0, bl, acc0, 0, 0, 0);
      acc0 = __builtin_amdgcn_mfma_f32_32x32x16_bf16(al0, bh, acc0, 0, 0, 0);
      if constexpr (MT == 128){
        bf16x8 ah1 = *(const bf16x8*)(bufc + a1r * 64 + ((t0 ^ xa) << 4));
        bf16x8 al1 = *(const bf16x8*)(bufc + XROWB + a1r * 64 + ((t0 ^ xa) << 4));
        acc1 = __builtin_amdgcn_mfma_f32_32x32x16_bf16(ah1, bh, acc1, 0, 0, 0);
        acc1 = __builtin_amdgcn_mfma_f32_32x32x16_bf16(ah1, bl, acc1, 0, 0, 0);
        acc1 = __builtin_amdgcn_mfma_f32_32x32x16_bf16(al1, bh, acc1, 0, 0, 0);
      }
    }
  }
  __syncthreads();  // drains lgkm/vm + barrier: safe to alias sG over staging buffers

  // ---- epilogue: gate exchange via LDS, cell update, split-write h ----
  #pragma unroll
  for (int r = 0; r < 16; ++r){
    const int mm = (r & 3) + 8 * (r >> 2) + 4 * thalf;
    if constexpr (MT == 128){
      sG[wm * 64 + mm][wn * 32 + ml]      = acc0[r];
      sG[wm * 64 + 32 + mm][wn * 32 + ml] = acc1[r];
    } else {
      sG[wm * 32 + mm][wn * 32 + ml]      = acc0[r];
    }
  }
  __syncthreads();
  for (int e = tid; e < MT * 16; e += 256){
    const int m = e >> 4, u = e & 15;
    const int gj = u0 + u;
    float gi = sG[m][u]      + bias[gj];
    float gf = sG[m][16 + u] + bias[HH + gj];
    float gg = sG[m][32 + u] + bias[2 * HH + gj];
    float go = sG[m][48 + u] + bias[3 * HH + gj];
    if (Gin){
      const float* gb = Gin + (size_t)(m0 + m) * G4;
      gi += gb[gj]; gf += gb[HH + gj]; gg += gb[2 * HH + gj]; go += gb[3 * HH + gj];
    }
    const float si = 1.f / (1.f + expf(-gi));
    const float sf = 1.f / (1.f + expf(-gf));
    const float so = 1.f / (1.f + expf(-go));
    const size_t sidx = (size_t)(m0 + m) * HH + gj;
    const float cn = sf * cst[sidx] + si * tanhf(gg);
    const float hn = so * tanhf(cn);
    cst[sidx] = cn;
    u16 hh, hl; splitf(hn, hh, hl);
    Hnh[sidx] = hh; Hnl[sidx] = hl;
  }
}

// ---------- partial-gate GEMM: Gout[b][g*512+u] = X @ W^T (M=64 tile, K=512) ----------
__device__ __forceinline__ void part_body(
    char* smem, int bx,
    const u16* __restrict__ Xh, const u16* __restrict__ Xl,
    const u16* __restrict__ W_h, const u16* __restrict__ W_l,
    float* __restrict__ Gout)
{
  constexpr int XROWB = 64 * 64;
  constexpr int BUFB  = 2 * XROWB + 8192;
  constexpr int WH_O  = 2 * XROWB;
  constexpr int WL_O  = 2 * XROWB + 4096;

  const int tid  = threadIdx.x;
  const int lane = tid & 63;
  const int wid  = tid >> 6;
  const int wm = wid >> 1, wn = wid & 1;
  const int m0 = (bx >> 5) * 64;
  const int u0 = (bx & 31) * 16;

  floatx16 acc0 = {0.f,0.f,0.f,0.f,0.f,0.f,0.f,0.f,0.f,0.f,0.f,0.f,0.f,0.f,0.f,0.f};

  const int ml    = lane & 31;
  const int thalf = lane >> 5;
  const int a0r = wm * 32 + ml;
  const int brw = wn * 32 + ml;
  const int xa  = (a0r >> 1) & 3;
  const int xb  = (brw >> 1) & 3;

  const int sl  = lane & 3;
  const int rq  = lane >> 2;
  const int rx0 = wid * 16 + rq;
  const int rw  = wid * 16 + rq;
  const int sgx = (sl ^ ((rx0 >> 1) & 3)) << 4;
  const int sgw = (sl ^ ((rw  >> 1) & 3)) << 4;
  const size_t gxr0 = (size_t)(m0 + rx0);
  const size_t gwr  = (size_t)wid * HH + u0 + rq;
  const int oX = wid * 16 * 64;
  const int oW = wid * 16 * 64;

  auto stage = [&](int ch){
    const int k0 = ch << 5;
    char* b = smem + (ch & 3) * BUFB;
    gload16((const char*)(Xh + gxr0 * HH + k0) + sgx, b + oX);
    gload16((const char*)(Xl + gxr0 * HH + k0) + sgx, b + XROWB + oX);
    gload16((const char*)(W_h + gwr * HH + k0) + sgw, b + WH_O + oW);
    gload16((const char*)(W_l + gwr * HH + k0) + sgw, b + WL_O + oW);
  };

  stage(0); stage(1); stage(2);
  for (int ch = 0; ch < 16; ++ch){
    const int rem = (15 - ch) < 2 ? (15 - ch) : 2;
    __builtin_amdgcn_sched_barrier(0);
    if      (rem == 2) asm volatile("s_waitcnt vmcnt(8)" ::: "memory");
    else if (rem == 1) asm volatile("s_waitcnt vmcnt(4)" ::: "memory");
    else               asm volatile("s_waitcnt vmcnt(0)" ::: "memory");
    asm volatile("s_waitcnt lgkmcnt(0)" ::: "memory");
    __builtin_amdgcn_s_barrier();
    __builtin_amdgcn_sched_barrier(0);
    if (ch + 3 < 16) stage(ch + 3);
    const char* bufc = smem + (ch & 3) * BUFB;
    #pragma unroll
    for (int kk2 = 0; kk2 < 2; ++kk2){
      const int t0 = kk2 * 2 + thalf;
      bf16x8 ah0 = *(const bf16x8*)(bufc + a0r * 64 + ((t0 ^ xa) << 4));
      bf16x8 al0 = *(const bf16x8*)(bufc + XROWB + a0r * 64 + ((t0 ^ xa) << 4));
      bf16x8 bh  = *(const bf16x8*)(bufc + WH_O + brw * 64 + ((t0 ^ xb) << 4));
      bf16x8 bl  = *(const bf16x8*)(bufc + WL_O + brw * 64 + ((t0 ^ xb) << 4));
      acc0 = __builtin_amdgcn_mfma_f32_32x32x16_bf16(ah0, bh, acc0, 0, 0, 0);
      acc0 = __builtin_amdgcn_mfma_f32_32x32x16_bf16(ah0, bl, acc0, 0, 0, 0);
      acc0 = __builtin_amdgcn_mfma_f32_32x32x16_bf16(al0, bh, acc0, 0, 0, 0);
    }
  }
  // direct fp32 store: C col c -> gate (c>>4), unit u0+(c&15)
  const int c = wn * 32 + ml;
  const size_t gcolo = (size_t)(c >> 4) * HH + u0 + (c & 15);
  #pragma unroll
  for (int r = 0; r < 16; ++r){
    const int mm = (r & 3) + 8 * (r >> 2) + 4 * thalf;
    Gout[(size_t)(m0 + wm * 32 + mm) * G4 + gcolo] = acc0[r];
  }
}

// decoder combined launch: blocks [0,256) = cell-finish (K=512 or EPAD), [256,512) = partial GEMM
__global__ __launch_bounds__(256) void dec_ab(
    const u16* Xfh, const u16* Xfl, int Kf,
    const u16* Wf_h, const u16* Wf_l,
    const float* bias, const float* Gin,
    u16* Hnh, u16* Hnl, float* cst,
    const u16* Xph, const u16* Xpl,
    const u16* Wp_h, const u16* Wp_l,
    float* Gout)
{
  extern __shared__ char smem[];
  if (blockIdx.x < 256)
    lstm_body<64>(smem, blockIdx.x, Xfh, Xfl, Kf, Wf_h, Wf_l, nullptr, nullptr,
                  bias, Gin, nullptr, nullptr, Hnh, Hnl, cst);
  else
    part_body(smem, blockIdx.x - 256, Xph, Xpl, Wp_h, Wp_l, Gout);
}

// standalone partial (decoder prologue)
__global__ __launch_bounds__(256) void part_only(
    const u16* Xh, const u16* Xl, const u16* W_h, const u16* W_l, float* Gout)
{
  extern __shared__ char smem[];
  part_body(smem, blockIdx.x, Xh, Xl, W_h, W_l, Gout);
}

// Fused encoder step: blocks [0,128) = cell0(t), [128,256) = cell1(t-1). M=128 tiles.
__global__ __launch_bounds__(256) void lstm_pair(
    int act0, const u16* X0h, const u16* X0l,
    const u16* W0ih_h, const u16* W0ih_l, const u16* W0hh_h, const u16* W0hh_l,
    const float* b0, const u16* H0ph, const u16* H0pl, u16* H0nh, u16* H0nl, float* c0,
    int act1, const u16* X1h, const u16* X1l,
    const u16* W1ih_h, const u16* W1ih_l, const u16* W1hh_h, const u16* W1hh_l,
    const float* b1, const u16* H1ph, const u16* H1pl, u16* H1nh, u16* H1nl, float* c1)
{
  extern __shared__ char smem[];
  const int half = blockIdx.x >> 7;
  const int bx   = blockIdx.x & 127;
  if (half == 0 ? !act0 : !act1) return;
  lstm_body<128>(smem, bx,
                 half ? X1h : X0h, half ? X1l : X0l, half ? HH : EPAD,
                 half ? W1ih_h : W0ih_h, half ? W1ih_l : W0ih_l,
                 half ? W1hh_h : W0hh_h, half ? W1hh_l : W0hh_l,
                 half ? b1 : b0, nullptr,
                 half ? H1ph : H0ph, half ? H1pl : H0pl,
                 half ? H1nh : H0nh, half ? H1nl : H0nl,
                 half ? c1 : c0);
}

// ---------- batched FC over all decoder steps (unchanged, proven) ----------
__global__ __launch_bounds__(256) void fc_batch(
    const u16* __restrict__ Hh, const u16* __restrict__ Hl,
    const u16* __restrict__ Wh, const u16* __restrict__ Wl,
    const float* __restrict__ bfc,
    float* __restrict__ out)
{
  extern __shared__ char smem[];
  const int tid = threadIdx.x, lane = tid & 63, wid = tid >> 6;
  const int wm = wid >> 1, wn = wid & 1;
  const int m0 = blockIdx.x * 128;      // row = p*512 + b
  const int n0 = blockIdx.y * 64;

  floatx16 acc0 = {0.f,0.f,0.f,0.f,0.f,0.f,0.f,0.f,0.f,0.f,0.f,0.f,0.f,0.f,0.f,0.f};
  floatx16 acc1 = {0.f,0.f,0.f,0.f,0.f,0.f,0.f,0.f,0.f,0.f,0.f,0.f,0.f,0.f,0.f,0.f};

  const int ml    = lane & 31;
  const int thalf = lane >> 5;
  const int a0r = wm * 64 + ml;
  const int a1r = a0r + 32;
  const int brw = wn * 32 + ml;
  const int xa  = (a0r >> 1) & 3;
  const int xb  = (brw >> 1) & 3;

  const int sl  = lane & 3;
  const int rq  = lane >> 2;
  const int rx0 = wid * 32 + rq;
  const int rw  = wid * 16 + rq;
  const int sgx = (sl ^ ((rx0 >> 1) & 3)) << 4;
  const int sgw = (sl ^ ((rw  >> 1) & 3)) << 4;
  const size_t gxr0 = (size_t)(m0 + rx0);
  const size_t gxr1 = gxr0 + 16;
  const size_t gwr  = (size_t)(n0 + rw);
  const int oX = wid * 32 * 64;
  const int oW = wid * 16 * 64;

  auto stage = [&](int ch){
    const int k0 = ch << 5;
    char* b = smem + (ch & 1) * BUF_SZ;
    gload16((const char*)(Hh + gxr0 * HH + k0) + sgx, b + XH_OFF + oX);
    gload16((const char*)(Hh + gxr1 * HH + k0) + sgx, b + XH_OFF + oX + 1024);
    gload16((const char*)(Hl + gxr0 * HH + k0) + sgx, b + XL_OFF + oX);
    gload16((const char*)(Hl + gxr1 * HH + k0) + sgx, b + XL_OFF + oX + 1024);
    gload16((const char*)(Wh + gwr  * HH + k0) + sgw, b + WH_OFF + oW);
    gload16((const char*)(Wl + gwr  * HH + k0) + sgw, b + WL_OFF + oW);
  };

  stage(0);
  for (int ch = 0; ch < 16; ++ch){
    if (ch + 1 < 16) stage(ch + 1);
    __builtin_amdgcn_sched_barrier(0);
    if (ch + 1 < 16) { asm volatile("s_waitcnt vmcnt(6)" ::: "memory"); }
    else             { asm volatile("s_waitcnt vmcnt(0)" ::: "memory"); }
    __builtin_amdgcn_s_barrier();
    __builtin_amdgcn_sched_barrier(0);
    const char* bufc = smem + (ch & 1) * BUF_SZ;
    #pragma unroll
    for (int kk2 = 0; kk2 < 2; ++kk2){
      const int t0 = kk2 * 2 + thalf;
      bf16x8 ah0 = *(const bf16x8*)(bufc + XH_OFF + a0r * 64 + ((t0 ^ xa) << 4));
      bf16x8 al0 = *(const bf16x8*)(bufc + XL_OFF + a0r * 64 + ((t0 ^ xa) << 4));
      bf16x8 ah1 = *(const bf16x8*)(bufc + XH_OFF + a1r * 64 + ((t0 ^ xa) << 4));
      bf16x8 al1 = *(const bf16x8*)(bufc + XL_OFF + a1r * 64 + ((t0 ^ xa) << 4));
      bf16x8 bh  = *(const bf16x8*)(bufc + WH_OFF + brw * 64 + ((t0 ^ xb) << 4));
      bf16x8 bl  = *(const bf16x8*)(bufc + WL_OFF + brw * 64 + ((t0 ^ xb) << 4));
      acc0 = __builtin_amdgcn_mfma_f32_32x32x16_bf16(ah0, bh, acc0, 0, 0, 0);
      acc0 = __builtin_amdgcn_mfma_f32_32x32x16_bf16(ah0, bl, acc0, 0, 0, 0);
      acc0 = __builtin_amdgcn_mfma_f32_32x32x16_bf16(al0, bh, acc0, 0, 0, 0);
      acc1 = __builtin_amdgcn_mfma_f32_32x32x16_bf16(ah1, bh, acc1, 0, 0, 0);
      acc1 = __builtin_amdgcn_mfma_f32_32x32x16_bf16(ah1, bl, acc1, 0, 0, 0);
      acc1 = __builtin_amdgcn_mfma_f32_32x32x16_bf16(al1, bh, acc1, 0, 0, 0);
    }
    __builtin_amdgcn_sched_barrier(0);
    asm volatile("s_waitcnt lgkmcnt(0)" ::: "memory");
    __builtin_amdgcn_s_barrier();
    __builtin_amdgcn_sched_barrier(0);
  }

  const int n = n0 + wn * 32 + ml;
  if (n < CC){
    const float bv = bfc[n];
    #pragma unroll
    for (int r = 0; r < 16; ++r){
      const int mm = (r & 3) + 8 * (r >> 2) + 4 * thalf;
      {
        const int rr = m0 + wm * 64 + mm;
        out[(size_t)(rr & 511) * PP * CC + (size_t)(rr >> 9) * CC + n] = acc0[r] + bv;
      }
      {
        const int rr = m0 + wm * 64 + 32 + mm;
        out[(size_t)(rr & 511) * PP * CC + (size_t)(rr >> 9) * CC + n] = acc1[r] + bv;
      }
    }
  }
}

extern "C" void kernel_launch(void* const* d_in, const int* in_sizes, int n_in,
                              void* d_out, int out_size, void* d_ws, size_t ws_size,
                              hipStream_t stream) {
  const float* x_enc  = (const float*)d_in[0];
  const float* e_Wih0 = (const float*)d_in[4];
  const float* e_Whh0 = (const float*)d_in[5];
  const float* e_bih0 = (const float*)d_in[6];
  const float* e_bhh0 = (const float*)d_in[7];
  const float* e_Wih1 = (const float*)d_in[8];
  const float* e_Whh1 = (const float*)d_in[9];
  const float* e_bih1 = (const float*)d_in[10];
  const float* e_bhh1 = (const float*)d_in[11];
  const float* d_Wih0 = (const float*)d_in[12];
  const float* d_Whh0 = (const float*)d_in[13];
  const float* d_bih0 = (const float*)d_in[14];
  const float* d_bhh0 = (const float*)d_in[15];
  const float* d_Wih1 = (const float*)d_in[16];
  const float* d_Whh1 = (const float*)d_in[17];
  const float* d_bih1 = (const float*)d_in[18];
  const float* d_bhh1 = (const float*)d_in[19];
  const float* fc_W   = (const float*)d_in[20];
  const float* fc_b   = (const float*)d_in[21];

  static bool attr_done = false;
  if (!attr_done){
    hipFuncSetAttribute((const void*)lstm_pair, hipFuncAttributeMaxDynamicSharedMemorySize, SMEM128);
    hipFuncSetAttribute((const void*)dec_ab,    hipFuncAttributeMaxDynamicSharedMemorySize, DEC_SMEM);
    hipFuncSetAttribute((const void*)part_only, hipFuncAttributeMaxDynamicSharedMemorySize, DEC_SMEM);
    attr_done = true;
  }

  char* base = (char*)d_ws;
  size_t off = 0;
  auto alloc_us = [&](size_t n){ u16* p = (u16*)(base + off); off += ((n * 2 + 15) & ~(size_t)15); return p; };
  auto alloc_f  = [&](size_t n){ float* p = (float*)(base + off); off += ((n * 4 + 15) & ~(size_t)15); return p; };

  u16 *We0ih_h = alloc_us((size_t)G4 * EPAD), *We0ih_l = alloc_us((size_t)G4 * EPAD);
  u16 *We0hh_h = alloc_us((size_t)G4 * HH),   *We0hh_l = alloc_us((size_t)G4 * HH);
  u16 *We1ih_h = alloc_us((size_t)G4 * HH),   *We1ih_l = alloc_us((size_t)G4 * HH);
  u16 *We1hh_h = alloc_us((size_t)G4 * HH),   *We1hh_l = alloc_us((size_t)G4 * HH);
  u16 *Wd0ih_h = alloc_us((size_t)G4 * EPAD), *Wd0ih_l = alloc_us((size_t)G4 * EPAD);
  u16 *Wd0hh_h = alloc_us((size_t)G4 * HH),   *Wd0hh_l = alloc_us((size_t)G4 * HH);
  u16 *Wd1ih_h = alloc_us((size_t)G4 * HH),   *Wd1ih_l = alloc_us((size_t)G4 * HH);
  u16 *Wd1hh_h = alloc_us((size_t)G4 * HH),   *Wd1hh_l = alloc_us((size_t)G4 * HH);
  u16 *Wfc_h   = alloc_us((size_t)NFC * HH),  *Wfc_l   = alloc_us((size_t)NFC * HH);
  u16 *Wc_h    = alloc_us((size_t)G4 * HH),   *Wc_l    = alloc_us((size_t)G4 * HH);
  float* be0 = alloc_f(G4);
  float* be1 = alloc_f(G4);
  float* bd0 = alloc_f(G4);
  float* bd1 = alloc_f(G4);
  float* bfc = alloc_f(NFC);
  float* bd0c = alloc_f(G4);
  float* Wcf32 = alloc_f((size_t)G4 * HH);
  float* Gp0 = alloc_f((size_t)BB * G4);
  float* Gp1 = alloc_f((size_t)BB * G4);
  // zero-init region: h0[0], h1[0] (hi+lo) then c0, c1 — one memset covers all
  u16* h0h[2]; u16* h0l[2]; u16* h1h[2]; u16* h1l[2];
  h0h[0] = alloc_us((size_t)BB * HH); h0l[0] = alloc_us((size_t)BB * HH);
  h1h[0] = alloc_us((size_t)BB * HH); h1l[0] = alloc_us((size_t)BB * HH);
  float* c0 = alloc_f((size_t)BB * HH);
  float* c1 = alloc_f((size_t)BB * HH);
  h0h[1] = alloc_us((size_t)BB * HH); h0l[1] = alloc_us((size_t)BB * HH);
  h1h[1] = alloc_us((size_t)BB * HH); h1l[1] = alloc_us((size_t)BB * HH);
  u16* inph = alloc_us((size_t)BB * EPAD);
  u16* inpl = alloc_us((size_t)BB * EPAD);
  u16* Xench = alloc_us((size_t)TT * BB * EPAD);
  u16* Xencl = alloc_us((size_t)TT * BB * EPAD);
  u16* histh = alloc_us((size_t)PP * BB * HH);
  u16* histl = alloc_us((size_t)PP * BB * HH);

  // prep
  cvt_split<<<512, 256, 0, stream>>>(e_Wih0, We0ih_h, We0ih_l, G4, EE, G4, EPAD);
  cvt_split<<<512, 256, 0, stream>>>(e_Whh0, We0hh_h, We0hh_l, G4, HH, G4, HH);
  cvt_split<<<512, 256, 0, stream>>>(e_Wih1, We1ih_h, We1ih_l, G4, HH, G4, HH);
  cvt_split<<<512, 256, 0, stream>>>(e_Whh1, We1hh_h, We1hh_l, G4, HH, G4, HH);
  cvt_split<<<512, 256, 0, stream>>>(d_Wih0, Wd0ih_h, Wd0ih_l, G4, EE, G4, EPAD);
  cvt_split<<<512, 256, 0, stream>>>(d_Whh0, Wd0hh_h, Wd0hh_l, G4, HH, G4, HH);
  cvt_split<<<512, 256, 0, stream>>>(d_Wih1, Wd1ih_h, Wd1ih_l, G4, HH, G4, HH);
  cvt_split<<<512, 256, 0, stream>>>(d_Whh1, Wd1hh_h, Wd1hh_l, G4, HH, G4, HH);
  cvt_split<<<512, 256, 0, stream>>>(fc_W,   Wfc_h,   Wfc_l,   CC, HH, NFC, HH);
  cvt_bias<<<8, 256, 0, stream>>>(e_bih0, e_bhh0, be0, G4, G4);
  cvt_bias<<<8, 256, 0, stream>>>(e_bih1, e_bhh1, be1, G4, G4);
  cvt_bias<<<8, 256, 0, stream>>>(d_bih0, d_bhh0, bd0, G4, G4);
  cvt_bias<<<8, 256, 0, stream>>>(d_bih1, d_bhh1, bd1, G4, G4);
  cvt_bias<<<2, 256, 0, stream>>>(fc_b, nullptr, bfc, CC, NFC);
  wcomb<<<G4, 256, 0, stream>>>(d_Wih0, fc_W, Wcf32);
  bias_fold<<<8, 256, 0, stream>>>(bd0, d_Wih0, fc_b, bd0c);
  cvt_split<<<512, 256, 0, stream>>>(Wcf32, Wc_h, Wc_l, G4, HH, G4, HH);
  hipMemsetAsync(h0h[0], 0, (size_t)4 * BB * HH * sizeof(u16) + (size_t)2 * BB * HH * sizeof(float), stream);
  init_inp<<<512, 256, 0, stream>>>(x_enc, inph, inpl);
  split_xenc<<<4096, 256, 0, stream>>>(x_enc, Xench, Xencl);

  // encoder: fused pipeline, iteration t runs cell0(t) and cell1(t-1)
  for (int t = 0; t <= TT; ++t){
    const int rd = t & 1, wrp = (t + 1) & 1;
    const size_t ts = (size_t)(t < TT ? t : 0) * BB * EPAD;
    lstm_pair<<<256, 256, SMEM128, stream>>>(
        (t < TT) ? 1 : 0, Xench + ts, Xencl + ts,
        We0ih_h, We0ih_l, We0hh_h, We0hh_l, be0,
        h0h[rd], h0l[rd], h0h[wrp], h0l[wrp], c0,
        (t > 0) ? 1 : 0, h0h[rd], h0l[rd],
        We1ih_h, We1ih_l, We1hh_h, We1hh_l, be1,
        h1h[wrp], h1l[wrp], h1h[rd], h1l[rd], c1);
  }
  // encoder finals land at parity 0 for both h0 and h1

  // decoder: split-overlap schedule. A(p)={fin0 (K=512/EPAD, +Gp0)} ∥ {part1: h1(p-1)@Whh1 -> Gp1}
  //          B(p)={fin1 (K=512, +Gp1), writes hist[p]} ∥ {part0: h0(p)@Whh0 -> Gp0}
  const size_t S = (size_t)BB * HH;
  part_only<<<256, 256, DEC_SMEM, stream>>>(h0h[0], h0l[0], Wd0hh_h, Wd0hh_l, Gp0);
  for (int p = 0; p < PP; ++p){
    const u16* hp_h = p ? histh + (size_t)(p - 1) * S : h1h[0];
    const u16* hp_l = p ? histl + (size_t)(p - 1) * S : h1l[0];
    dec_ab<<<512, 256, DEC_SMEM, stream>>>(
        p ? hp_h : inph, p ? hp_l : inpl, p ? HH : EPAD,
        p ? Wc_h : Wd0ih_h, p ? Wc_l : Wd0ih_l,
        p ? bd0c : bd0, Gp0,
        h0h[1], h0l[1], c0,
        hp_h, hp_l, Wd1hh_h, Wd1hh_l, Gp1);
    dec_ab<<<512, 256, DEC_SMEM, stream>>>(
        h0h[1], h0l[1], HH,
        Wd1ih_h, Wd1ih_l,
        bd1, Gp1,
        histh + (size_t)p * S, histl + (size_t)p * S, c1,
        h0h[1], h0l[1], Wd0hh_h, Wd0hh_l, Gp0);
  }

  // batched FC over all 96 decoder steps
  fc_batch<<<dim3((PP * BB) / 128, NFC / 64), 256, FC_SMEM, stream>>>(
      histh, histl, Wfc_h, Wfc_l, bfc, (float*)d_out);
}

// Round 7
// 5713.681 us; speedup vs baseline: 2.2335x; 1.0272x over previous
//
#include <hip/hip_runtime.h>
#include <hip/hip_bf16.h>

#define BB 512     // batch
#define TT 96      // encoder steps
#define PP 96      // decoder steps
#define EE 321     // input features
#define CC 321     // output channels
#define HH 512     // hidden
#define G4 2048    // 4*H
#define EPAD 352   // 321 padded to 32
#define NFC 384    // fc N pad (64-multiple)

// fc_batch (2-deep) staging
#define BUF_SZ 24576
#define XH_OFF 0
#define XL_OFF 8192
#define WH_OFF 16384
#define WL_OFF 20480
#define FC_SMEM 49152

// lstm M=64: 4-deep pipeline, 4 x (2*4096 + 8192) = 64KB -> 2 blocks/CU
#define DEC_SMEM 65536

typedef unsigned short u16;
typedef __attribute__((ext_vector_type(8))) short bf16x8;
typedef __attribute__((ext_vector_type(16))) float floatx16;

__device__ __forceinline__ void splitf(float v, u16& h, u16& l){
  __hip_bfloat16 bh = __float2bfloat16(v);
  h = *reinterpret_cast<u16*>(&bh);
  float r = v - __bfloat162float(bh);
  __hip_bfloat16 bl = __float2bfloat16(r);
  l = *reinterpret_cast<u16*>(&bl);
}

// async global->LDS, 16B per lane; LDS dest = wave-uniform base + lane*16 (linear).
__device__ __forceinline__ void gload16(const void* g, void* l){
  __builtin_amdgcn_global_load_lds((const __attribute__((address_space(1))) void*)g,
                                   (__attribute__((address_space(3))) void*)l, 16, 0, 0);
}

// ---------- fused prep ----------
struct SJob { const float* src; u16* hi; u16* lo; int rows, cols, rowspad, colspad; };
struct SJobs { SJob j[9]; };

// all 9 weight splits in one launch (grid-stride per job)
__global__ void split_multi(SJobs js){
  const int stride = gridDim.x * blockDim.x;
  const int t0 = blockIdx.x * blockDim.x + threadIdx.x;
  for (int k = 0; k < 9; ++k){
    const SJob J = js.j[k];
    const int total = J.rowspad * J.colspad;
    for (int idx = t0; idx < total; idx += stride){
      int r = idx / J.colspad, cc = idx - r * J.colspad;
      float v = (r < J.rows && cc < J.cols) ? J.src[(size_t)r * J.cols + cc] : 0.f;
      u16 h, l; splitf(v, h, l);
      J.hi[idx] = h; J.lo[idx] = l;
    }
  }
}

// Wcomb = Wd0ih @ fcW, split to bf16 hi/lo directly; bd0c = (d_bih0+d_bhh0) + Wd0ih @ fcb
__global__ void wcomb_fused(const float* __restrict__ A,    // [2048][321] d_Wih0
                            const float* __restrict__ Bm,   // [321][512]  fc_W
                            const float* __restrict__ bih, const float* __restrict__ bhh,
                            const float* __restrict__ fcb,
                            u16* __restrict__ Wc_h, u16* __restrict__ Wc_l,
                            float* __restrict__ bd0c){
  __shared__ float arow[EE];
  __shared__ float red[256];
  const int g = blockIdx.x;
  for (int e = threadIdx.x; e < EE; e += 256) arow[e] = A[(size_t)g * EE + e];
  __syncthreads();
  float ps = 0.f;
  for (int e = threadIdx.x; e < EE; e += 256) ps += arow[e] * fcb[e];
  red[threadIdx.x] = ps; __syncthreads();
  for (int s = 128; s > 0; s >>= 1){
    if (threadIdx.x < s) red[threadIdx.x] += red[threadIdx.x + s];
    __syncthreads();
  }
  if (threadIdx.x == 0) bd0c[g] = bih[g] + bhh[g] + red[0];
  for (int k = threadIdx.x; k < HH; k += 256){
    float s = 0.f;
    for (int e = 0; e < EE; ++e) s += arow[e] * Bm[(size_t)e * HH + k];
    u16 h, l; splitf(s, h, l);
    Wc_h[(size_t)g * HH + k] = h; Wc_l[(size_t)g * HH + k] = l;
  }
}

// biases + inp split + x_enc re-layout split, one launch
__global__ void prep_misc(
    const float* e_bih0, const float* e_bhh0, float* be0,
    const float* e_bih1, const float* e_bhh1, float* be1,
    const float* d_bih0, const float* d_bhh0, float* bd0,
    const float* d_bih1, const float* d_bhh1, float* bd1,
    const float* fc_b, float* bfc,
    const float* x_enc, u16* inph, u16* inpl, u16* xh, u16* xl){
  const int stride = gridDim.x * blockDim.x;
  const int t0 = blockIdx.x * blockDim.x + threadIdx.x;
  for (int i = t0; i < G4; i += stride){
    be0[i] = e_bih0[i] + e_bhh0[i];
    be1[i] = e_bih1[i] + e_bhh1[i];
    bd0[i] = d_bih0[i] + d_bhh0[i];
    bd1[i] = d_bih1[i] + d_bhh1[i];
  }
  for (int i = t0; i < NFC; i += stride) bfc[i] = (i < CC) ? fc_b[i] : 0.f;
  for (int idx = t0; idx < BB * EPAD; idx += stride){
    int b = idx / EPAD, j = idx - b * EPAD;
    float v = (j < EE) ? x_enc[(size_t)b * TT * EE + (size_t)(TT - 1) * EE + j] : 0.f;
    u16 h, l; splitf(v, h, l);
    inph[idx] = h; inpl[idx] = l;
  }
  for (int idx = t0; idx < TT * BB * EPAD; idx += stride){
    int e = idx % EPAD;
    int rest = idx / EPAD;
    int b = rest % BB;
    int t = rest / BB;
    float v = (e < EE) ? x_enc[((size_t)b * TT + t) * EE + e] : 0.f;
    u16 h, l; splitf(v, h, l);
    xh[idx] = h; xl[idx] = l;
  }
}

// ---------- LSTM cell body (proven round-4/5) ----------
// MT batch-rows x N=64 gate-cols. 4 waves. 4-deep gload_lds pipeline, counted vmcnt,
// ONE barrier per chunk. Hph==null => single-phase K. Gin!=null => add partial gates.
template<int MT>
__device__ __forceinline__ void lstm_body(
    char* smem, int bx,
    const u16* __restrict__ Xh, const u16* __restrict__ Xl, int K1pad,
    const u16* __restrict__ Wih_h, const u16* __restrict__ Wih_l,
    const u16* __restrict__ Whh_h, const u16* __restrict__ Whh_l,
    const float* __restrict__ bias, const float* __restrict__ Gin,
    const u16* __restrict__ Hph, const u16* __restrict__ Hpl,
    u16* __restrict__ Hnh, u16* __restrict__ Hnl,
    float* __restrict__ cst)
{
  constexpr int XROWB = MT * 64;
  constexpr int BUFB  = 2 * XROWB + 8192;
  constexpr int WH_O  = 2 * XROWB;
  constexpr int WL_O  = 2 * XROWB + 4096;

  float (*sG)[68] = (float (*)[68])(smem);   // aliases staging; used only after final syncthreads

  const int tid  = threadIdx.x;
  const int lane = tid & 63;
  const int wid  = tid >> 6;
  const int wm = wid >> 1, wn = wid & 1;
  const int m0 = (bx >> 5) * MT;
  const int u0 = (bx & 31) * 16;

  floatx16 acc0 = {0.f,0.f,0.f,0.f,0.f,0.f,0.f,0.f,0.f,0.f,0.f,0.f,0.f,0.f,0.f,0.f};
  floatx16 acc1 = acc0;   // dead (DCE'd) when MT==64

  const int ml    = lane & 31;
  const int thalf = lane >> 5;
  const int a0r = (MT == 128 ? wm * 64 : wm * 32) + ml;
  const int a1r = a0r + 32;                // MT==128 only
  const int brw = wn * 32 + ml;
  const int xa  = (a0r >> 1) & 3;
  const int xb  = (brw >> 1) & 3;

  const int sl  = lane & 3;
  const int rq  = lane >> 2;
  const int rx0 = wid * (MT / 4) + rq;
  const int rw  = wid * 16 + rq;
  const int sgx = (sl ^ ((rx0 >> 1) & 3)) << 4;
  const int sgw = (sl ^ ((rw  >> 1) & 3)) << 4;
  const size_t gxr0 = (size_t)(m0 + rx0);
  const size_t gxr1 = gxr0 + 16;                  // MT==128 only
  const size_t gwr  = (size_t)wid * HH + u0 + rq; // gate-row remap
  const int oX = wid * (MT / 4) * 64;
  const int oW = wid * 16 * 64;

  const int nch1 = K1pad >> 5;
  const int ncht = Hph ? nch1 + (HH >> 5) : nch1;  // >= 11 always

  auto stage = [&](int ch){
    const bool p1 = ch < nch1;
    const int k0 = (p1 ? ch : ch - nch1) << 5;
    const u16* xh = p1 ? Xh : Hph;
    const u16* xl = p1 ? Xl : Hpl;
    const u16* wh = p1 ? Wih_h : Whh_h;
    const u16* wl = p1 ? Wih_l : Whh_l;
    const size_t Kp = p1 ? (size_t)K1pad : (size_t)HH;
    char* b = smem + (ch & 3) * BUFB;
    gload16((const char*)(xh + gxr0 * Kp + k0) + sgx, b + oX);
    if constexpr (MT == 128) gload16((const char*)(xh + gxr1 * Kp + k0) + sgx, b + oX + 1024);
    gload16((const char*)(xl + gxr0 * Kp + k0) + sgx, b + XROWB + oX);
    if constexpr (MT == 128) gload16((const char*)(xl + gxr1 * Kp + k0) + sgx, b + XROWB + oX + 1024);
    gload16((const char*)(wh + gwr  * Kp + k0) + sgw, b + WH_O + oW);
    gload16((const char*)(wl + gwr  * Kp + k0) + sgw, b + WL_O + oW);
  };

  // prologue: 3 chunks in flight (ncht >= 11 always)
  stage(0); stage(1); stage(2);
  for (int ch = 0; ch < ncht; ++ch){
    const int rem = (ncht - 1 - ch) < 2 ? (ncht - 1 - ch) : 2;  // newer chunks in flight
    __builtin_amdgcn_sched_barrier(0);
    if constexpr (MT == 128){
      if      (rem == 2) asm volatile("s_waitcnt vmcnt(12)" ::: "memory");
      else if (rem == 1) asm volatile("s_waitcnt vmcnt(6)"  ::: "memory");
      else               asm volatile("s_waitcnt vmcnt(0)"  ::: "memory");
    } else {
      if      (rem == 2) asm volatile("s_waitcnt vmcnt(8)"  ::: "memory");
      else if (rem == 1) asm volatile("s_waitcnt vmcnt(4)"  ::: "memory");
      else               asm volatile("s_waitcnt vmcnt(0)"  ::: "memory");
    }
    asm volatile("s_waitcnt lgkmcnt(0)" ::: "memory");   // my ch-1 reads retired
    __builtin_amdgcn_s_barrier();                        // chunk ch resident; ch-1 reads globally done
    __builtin_amdgcn_sched_barrier(0);
    if (ch + 3 < ncht) stage(ch + 3);                    // writes buf (ch-1)&3: safe now
    const char* bufc = smem + (ch & 3) * BUFB;
    #pragma unroll
    for (int kk2 = 0; kk2 < 2; ++kk2){
      const int t0 = kk2 * 2 + thalf;
      bf16x8 ah0 = *(const bf16x8*)(bufc + a0r * 64 + ((t0 ^ xa) << 4));
      bf16x8 al0 = *(const bf16x8*)(bufc + XROWB + a0r * 64 + ((t0 ^ xa) << 4));
      bf16x8 bh  = *(const bf16x8*)(bufc + WH_O + brw * 64 + ((t0 ^ xb) << 4));
      bf16x8 bl  = *(const bf16x8*)(bufc + WL_O + brw * 64 + ((t0 ^ xb) << 4));
      acc0 = __builtin_amdgcn_mfma_f32_32x32x16_bf16(ah0, bh, acc0, 0, 0, 0);
      acc0 = __builtin_amdgcn_mfma_f32_32x32x16_bf16(ah0, bl, acc0, 0, 0, 0);
      acc0 = __builtin_amdgcn_mfma_f32_32x32x16_bf16(al0, bh, acc0, 0, 0, 0);
      if constexpr (MT == 128){
        bf16x8 ah1 = *(const bf16x8*)(bufc + a1r * 64 + ((t0 ^ xa) << 4));
        bf16x8 al1 = *(const bf16x8*)(bufc + XROWB + a1r * 64 + ((t0 ^ xa) << 4));
        acc1 = __builtin_amdgcn_mfma_f32_32x32x16_bf16(ah1, bh, acc1, 0, 0, 0);
        acc1 = __builtin_amdgcn_mfma_f32_32x32x16_bf16(ah1, bl, acc1, 0, 0, 0);
        acc1 = __builtin_amdgcn_mfma_f32_32x32x16_bf16(al1, bh, acc1, 0, 0, 0);
      }
    }
  }
  __syncthreads();  // drains lgkm/vm + barrier: safe to alias sG over staging buffers

  // ---- epilogue: gate exchange via LDS, cell update, split-write h ----
  #pragma unroll
  for (int r = 0; r < 16; ++r){
    const int mm = (r & 3) + 8 * (r >> 2) + 4 * thalf;
    if constexpr (MT == 128){
      sG[wm * 64 + mm][wn * 32 + ml]      = acc0[r];
      sG[wm * 64 + 32 + mm][wn * 32 + ml] = acc1[r];
    } else {
      sG[wm * 32 + mm][wn * 32 + ml]      = acc0[r];
    }
  }
  __syncthreads();
  for (int e = tid; e < MT * 16; e += 256){
    const int m = e >> 4, u = e & 15;
    const int gj = u0 + u;
    float gi = sG[m][u]      + bias[gj];
    float gf = sG[m][16 + u] + bias[HH + gj];
    float gg = sG[m][32 + u] + bias[2 * HH + gj];
    float go = sG[m][48 + u] + bias[3 * HH + gj];
    if (Gin){
      const float* gb = Gin + (size_t)(m0 + m) * G4;
      gi += gb[gj]; gf += gb[HH + gj]; gg += gb[2 * HH + gj]; go += gb[3 * HH + gj];
    }
    const float si = 1.f / (1.f + expf(-gi));
    const float sf = 1.f / (1.f + expf(-gf));
    const float so = 1.f / (1.f + expf(-go));
    const size_t sidx = (size_t)(m0 + m) * HH + gj;
    const float cn = sf * cst[sidx] + si * tanhf(gg);
    const float hn = so * tanhf(cn);
    cst[sidx] = cn;
    u16 hh, hl; splitf(hn, hh, hl);
    Hnh[sidx] = hh; Hnl[sidx] = hl;
  }
}

// ---------- partial-gate GEMM: Gout[b][g*512+u] = X @ W^T (M=64 tile, K=512) ----------
__device__ __forceinline__ void part_body(
    char* smem, int bx,
    const u16* __restrict__ Xh, const u16* __restrict__ Xl,
    const u16* __restrict__ W_h, const u16* __restrict__ W_l,
    float* __restrict__ Gout)
{
  constexpr int XROWB = 64 * 64;
  constexpr int BUFB  = 2 * XROWB + 8192;
  constexpr int WH_O  = 2 * XROWB;
  constexpr int WL_O  = 2 * XROWB + 4096;

  const int tid  = threadIdx.x;
  const int lane = tid & 63;
  const int wid  = tid >> 6;
  const int wm = wid >> 1, wn = wid & 1;
  const int m0 = (bx >> 5) * 64;
  const int u0 = (bx & 31) * 16;

  floatx16 acc0 = {0.f,0.f,0.f,0.f,0.f,0.f,0.f,0.f,0.f,0.f,0.f,0.f,0.f,0.f,0.f,0.f};

  const int ml    = lane & 31;
  const int thalf = lane >> 5;
  const int a0r = wm * 32 + ml;
  const int brw = wn * 32 + ml;
  const int xa  = (a0r >> 1) & 3;
  const int xb  = (brw >> 1) & 3;

  const int sl  = lane & 3;
  const int rq  = lane >> 2;
  const int rx0 = wid * 16 + rq;
  const int rw  = wid * 16 + rq;
  const int sgx = (sl ^ ((rx0 >> 1) & 3)) << 4;
  const int sgw = (sl ^ ((rw  >> 1) & 3)) << 4;
  const size_t gxr0 = (size_t)(m0 + rx0);
  const size_t gwr  = (size_t)wid * HH + u0 + rq;
  const int oX = wid * 16 * 64;
  const int oW = wid * 16 * 64;

  auto stage = [&](int ch){
    const int k0 = ch << 5;
    char* b = smem + (ch & 3) * BUFB;
    gload16((const char*)(Xh + gxr0 * HH + k0) + sgx, b + oX);
    gload16((const char*)(Xl + gxr0 * HH + k0) + sgx, b + XROWB + oX);
    gload16((const char*)(W_h + gwr * HH + k0) + sgw, b + WH_O + oW);
    gload16((const char*)(W_l + gwr * HH + k0) + sgw, b + WL_O + oW);
  };

  stage(0); stage(1); stage(2);
  for (int ch = 0; ch < 16; ++ch){
    const int rem = (15 - ch) < 2 ? (15 - ch) : 2;
    __builtin_amdgcn_sched_barrier(0);
    if      (rem == 2) asm volatile("s_waitcnt vmcnt(8)" ::: "memory");
    else if (rem == 1) asm volatile("s_waitcnt vmcnt(4)" ::: "memory");
    else               asm volatile("s_waitcnt vmcnt(0)" ::: "memory");
    asm volatile("s_waitcnt lgkmcnt(0)" ::: "memory");
    __builtin_amdgcn_s_barrier();
    __builtin_amdgcn_sched_barrier(0);
    if (ch + 3 < 16) stage(ch + 3);
    const char* bufc = smem + (ch & 3) * BUFB;
    #pragma unroll
    for (int kk2 = 0; kk2 < 2; ++kk2){
      const int t0 = kk2 * 2 + thalf;
      bf16x8 ah0 = *(const bf16x8*)(bufc + a0r * 64 + ((t0 ^ xa) << 4));
      bf16x8 al0 = *(const bf16x8*)(bufc + XROWB + a0r * 64 + ((t0 ^ xa) << 4));
      bf16x8 bh  = *(const bf16x8*)(bufc + WH_O + brw * 64 + ((t0 ^ xb) << 4));
      bf16x8 bl  = *(const bf16x8*)(bufc + WL_O + brw * 64 + ((t0 ^ xb) << 4));
      acc0 = __builtin_amdgcn_mfma_f32_32x32x16_bf16(ah0, bh, acc0, 0, 0, 0);
      acc0 = __builtin_amdgcn_mfma_f32_32x32x16_bf16(ah0, bl, acc0, 0, 0, 0);
      acc0 = __builtin_amdgcn_mfma_f32_32x32x16_bf16(al0, bh, acc0, 0, 0, 0);
    }
  }
  // direct fp32 store: C col c -> gate (c>>4), unit u0+(c&15)
  const int c = wn * 32 + ml;
  const size_t gcolo = (size_t)(c >> 4) * HH + u0 + (c & 15);
  #pragma unroll
  for (int r = 0; r < 16; ++r){
    const int mm = (r & 3) + 8 * (r >> 2) + 4 * thalf;
    Gout[(size_t)(m0 + wm * 32 + mm) * G4 + gcolo] = acc0[r];
  }
}

// standalone partial (decoder prologue)
__global__ __launch_bounds__(256) void part_only(
    const u16* Xh, const u16* Xl, const u16* W_h, const u16* W_l, float* Gout)
{
  extern __shared__ char smem[];
  part_body(smem, blockIdx.x, Xh, Xl, W_h, W_l, Gout);
}

// decoder combined launch: blocks [0,256) = cell-finish (K=512 or EPAD), [256,512) = partial GEMM
__global__ __launch_bounds__(256, 2) void dec_ab(
    const u16* Xfh, const u16* Xfl, int Kf,
    const u16* Wf_h, const u16* Wf_l,
    const float* bias, const float* Gin,
    u16* Hnh, u16* Hnl, float* cst,
    const u16* Xph, const u16* Xpl,
    const u16* Wp_h, const u16* Wp_l,
    float* Gout)
{
  extern __shared__ char smem[];
  if (blockIdx.x < 256)
    lstm_body<64>(smem, blockIdx.x, Xfh, Xfl, Kf, Wf_h, Wf_l, nullptr, nullptr,
                  bias, Gin, nullptr, nullptr, Hnh, Hnl, cst);
  else
    part_body(smem, blockIdx.x - 256, Xph, Xpl, Wp_h, Wp_l, Gout);
}

// Fused encoder step, M=64 tiles: blocks [0,256) = cell0(t), [256,512) = cell1(t-1).
// 2 blocks/CU -> the two cells' serial chains hide each other's latency.
__global__ __launch_bounds__(256, 2) void lstm_pair(
    int act0, const u16* X0h, const u16* X0l,
    const u16* W0ih_h, const u16* W0ih_l, const u16* W0hh_h, const u16* W0hh_l,
    const float* b0, const u16* H0ph, const u16* H0pl, u16* H0nh, u16* H0nl, float* c0,
    int act1, const u16* X1h, const u16* X1l,
    const u16* W1ih_h, const u16* W1ih_l, const u16* W1hh_h, const u16* W1hh_l,
    const float* b1, const u16* H1ph, const u16* H1pl, u16* H1nh, u16* H1nl, float* c1)
{
  extern __shared__ char smem[];
  const int half = blockIdx.x >> 8;
  const int bx   = blockIdx.x & 255;
  if (half == 0 ? !act0 : !act1) return;
  lstm_body<64>(smem, bx,
                half ? X1h : X0h, half ? X1l : X0l, half ? HH : EPAD,
                half ? W1ih_h : W0ih_h, half ? W1ih_l : W0ih_l,
                half ? W1hh_h : W0hh_h, half ? W1hh_l : W0hh_l,
                half ? b1 : b0, nullptr,
                half ? H1ph : H0ph, half ? H1pl : H0pl,
                half ? H1nh : H0nh, half ? H1nl : H0nl,
                half ? c1 : c0);
}

// ---------- batched FC over all decoder steps (unchanged, proven) ----------
__global__ __launch_bounds__(256) void fc_batch(
    const u16* __restrict__ Hh, const u16* __restrict__ Hl,
    const u16* __restrict__ Wh, const u16* __restrict__ Wl,
    const float* __restrict__ bfc,
    float* __restrict__ out)
{
  extern __shared__ char smem[];
  const int tid = threadIdx.x, lane = tid & 63, wid = tid >> 6;
  const int wm = wid >> 1, wn = wid & 1;
  const int m0 = blockIdx.x * 128;      // row = p*512 + b
  const int n0 = blockIdx.y * 64;

  floatx16 acc0 = {0.f,0.f,0.f,0.f,0.f,0.f,0.f,0.f,0.f,0.f,0.f,0.f,0.f,0.f,0.f,0.f};
  floatx16 acc1 = {0.f,0.f,0.f,0.f,0.f,0.f,0.f,0.f,0.f,0.f,0.f,0.f,0.f,0.f,0.f,0.f};

  const int ml    = lane & 31;
  const int thalf = lane >> 5;
  const int a0r = wm * 64 + ml;
  const int a1r = a0r + 32;
  const int brw = wn * 32 + ml;
  const int xa  = (a0r >> 1) & 3;
  const int xb  = (brw >> 1) & 3;

  const int sl  = lane & 3;
  const int rq  = lane >> 2;
  const int rx0 = wid * 32 + rq;
  const int rw  = wid * 16 + rq;
  const int sgx = (sl ^ ((rx0 >> 1) & 3)) << 4;
  const int sgw = (sl ^ ((rw  >> 1) & 3)) << 4;
  const size_t gxr0 = (size_t)(m0 + rx0);
  const size_t gxr1 = gxr0 + 16;
  const size_t gwr  = (size_t)(n0 + rw);
  const int oX = wid * 32 * 64;
  const int oW = wid * 16 * 64;

  auto stage = [&](int ch){
    const int k0 = ch << 5;
    char* b = smem + (ch & 1) * BUF_SZ;
    gload16((const char*)(Hh + gxr0 * HH + k0) + sgx, b + XH_OFF + oX);
    gload16((const char*)(Hh + gxr1 * HH + k0) + sgx, b + XH_OFF + oX + 1024);
    gload16((const char*)(Hl + gxr0 * HH + k0) + sgx, b + XL_OFF + oX);
    gload16((const char*)(Hl + gxr1 * HH + k0) + sgx, b + XL_OFF + oX + 1024);
    gload16((const char*)(Wh + gwr  * HH + k0) + sgw, b + WH_OFF + oW);
    gload16((const char*)(Wl + gwr  * HH + k0) + sgw, b + WL_OFF + oW);
  };

  stage(0);
  for (int ch = 0; ch < 16; ++ch){
    if (ch + 1 < 16) stage(ch + 1);
    __builtin_amdgcn_sched_barrier(0);
    if (ch + 1 < 16) { asm volatile("s_waitcnt vmcnt(6)" ::: "memory"); }
    else             { asm volatile("s_waitcnt vmcnt(0)" ::: "memory"); }
    __builtin_amdgcn_s_barrier();
    __builtin_amdgcn_sched_barrier(0);
    const char* bufc = smem + (ch & 1) * BUF_SZ;
    #pragma unroll
    for (int kk2 = 0; kk2 < 2; ++kk2){
      const int t0 = kk2 * 2 + thalf;
      bf16x8 ah0 = *(const bf16x8*)(bufc + XH_OFF + a0r * 64 + ((t0 ^ xa) << 4));
      bf16x8 al0 = *(const bf16x8*)(bufc + XL_OFF + a0r * 64 + ((t0 ^ xa) << 4));
      bf16x8 ah1 = *(const bf16x8*)(bufc + XH_OFF + a1r * 64 + ((t0 ^ xa) << 4));
      bf16x8 al1 = *(const bf16x8*)(bufc + XL_OFF + a1r * 64 + ((t0 ^ xa) << 4));
      bf16x8 bh  = *(const bf16x8*)(bufc + WH_OFF + brw * 64 + ((t0 ^ xb) << 4));
      bf16x8 bl  = *(const bf16x8*)(bufc + WL_OFF + brw * 64 + ((t0 ^ xb) << 4));
      acc0 = __builtin_amdgcn_mfma_f32_32x32x16_bf16(ah0, bh, acc0, 0, 0, 0);
      acc0 = __builtin_amdgcn_mfma_f32_32x32x16_bf16(ah0, bl, acc0, 0, 0, 0);
      acc0 = __builtin_amdgcn_mfma_f32_32x32x16_bf16(al0, bh, acc0, 0, 0, 0);
      acc1 = __builtin_amdgcn_mfma_f32_32x32x16_bf16(ah1, bh, acc1, 0, 0, 0);
      acc1 = __builtin_amdgcn_mfma_f32_32x32x16_bf16(ah1, bl, acc1, 0, 0, 0);
      acc1 = __builtin_amdgcn_mfma_f32_32x32x16_bf16(al1, bh, acc1, 0, 0, 0);
    }
    __builtin_amdgcn_sched_barrier(0);
    asm volatile("s_waitcnt lgkmcnt(0)" ::: "memory");
    __builtin_amdgcn_s_barrier();
    __builtin_amdgcn_sched_barrier(0);
  }

  const int n = n0 + wn * 32 + ml;
  if (n < CC){
    const float bv = bfc[n];
    #pragma unroll
    for (int r = 0; r < 16; ++r){
      const int mm = (r & 3) + 8 * (r >> 2) + 4 * thalf;
      {
        const int rr = m0 + wm * 64 + mm;
        out[(size_t)(rr & 511) * PP * CC + (size_t)(rr >> 9) * CC + n] = acc0[r] + bv;
      }
      {
        const int rr = m0 + wm * 64 + 32 + mm;
        out[(size_t)(rr & 511) * PP * CC + (size_t)(rr >> 9) * CC + n] = acc1[r] + bv;
      }
    }
  }
}

extern "C" void kernel_launch(void* const* d_in, const int* in_sizes, int n_in,
                              void* d_out, int out_size, void* d_ws, size_t ws_size,
                              hipStream_t stream) {
  const float* x_enc  = (const float*)d_in[0];
  const float* e_Wih0 = (const float*)d_in[4];
  const float* e_Whh0 = (const float*)d_in[5];
  const float* e_bih0 = (const float*)d_in[6];
  const float* e_bhh0 = (const float*)d_in[7];
  const float* e_Wih1 = (const float*)d_in[8];
  const float* e_Whh1 = (const float*)d_in[9];
  const float* e_bih1 = (const float*)d_in[10];
  const float* e_bhh1 = (const float*)d_in[11];
  const float* d_Wih0 = (const float*)d_in[12];
  const float* d_Whh0 = (const float*)d_in[13];
  const float* d_bih0 = (const float*)d_in[14];
  const float* d_bhh0 = (const float*)d_in[15];
  const float* d_Wih1 = (const float*)d_in[16];
  const float* d_Whh1 = (const float*)d_in[17];
  const float* d_bih1 = (const float*)d_in[18];
  const float* d_bhh1 = (const float*)d_in[19];
  const float* fc_W   = (const float*)d_in[20];
  const float* fc_b   = (const float*)d_in[21];

  static bool attr_done = false;
  if (!attr_done){
    hipFuncSetAttribute((const void*)lstm_pair, hipFuncAttributeMaxDynamicSharedMemorySize, DEC_SMEM);
    hipFuncSetAttribute((const void*)part_only, hipFuncAttributeMaxDynamicSharedMemorySize, DEC_SMEM);
    hipFuncSetAttribute((const void*)dec_ab,    hipFuncAttributeMaxDynamicSharedMemorySize, DEC_SMEM);
    attr_done = true;
  }

  char* base = (char*)d_ws;
  size_t off = 0;
  auto alloc_us = [&](size_t n){ u16* p = (u16*)(base + off); off += ((n * 2 + 15) & ~(size_t)15); return p; };
  auto alloc_f  = [&](size_t n){ float* p = (float*)(base + off); off += ((n * 4 + 15) & ~(size_t)15); return p; };

  u16 *We0ih_h = alloc_us((size_t)G4 * EPAD), *We0ih_l = alloc_us((size_t)G4 * EPAD);
  u16 *We0hh_h = alloc_us((size_t)G4 * HH),   *We0hh_l = alloc_us((size_t)G4 * HH);
  u16 *We1ih_h = alloc_us((size_t)G4 * HH),   *We1ih_l = alloc_us((size_t)G4 * HH);
  u16 *We1hh_h = alloc_us((size_t)G4 * HH),   *We1hh_l = alloc_us((size_t)G4 * HH);
  u16 *Wd0ih_h = alloc_us((size_t)G4 * EPAD), *Wd0ih_l = alloc_us((size_t)G4 * EPAD);
  u16 *Wd0hh_h = alloc_us((size_t)G4 * HH),   *Wd0hh_l = alloc_us((size_t)G4 * HH);
  u16 *Wd1ih_h = alloc_us((size_t)G4 * HH),   *Wd1ih_l = alloc_us((size_t)G4 * HH);
  u16 *Wd1hh_h = alloc_us((size_t)G4 * HH),   *Wd1hh_l = alloc_us((size_t)G4 * HH);
  u16 *Wfc_h   = alloc_us((size_t)NFC * HH),  *Wfc_l   = alloc_us((size_t)NFC * HH);
  u16 *Wc_h    = alloc_us((size_t)G4 * HH),   *Wc_l    = alloc_us((size_t)G4 * HH);
  float* be0 = alloc_f(G4);
  float* be1 = alloc_f(G4);
  float* bd0 = alloc_f(G4);
  float* bd1 = alloc_f(G4);
  float* bfc = alloc_f(NFC);
  float* bd0c = alloc_f(G4);
  float* Gp0 = alloc_f((size_t)BB * G4);
  float* Gp1 = alloc_f((size_t)BB * G4);
  // zero-init region: h0[0], h1[0] (hi+lo) then c0, c1 — one memset covers all
  u16* h0h[2]; u16* h0l[2]; u16* h1h[2]; u16* h1l[2];
  h0h[0] = alloc_us((size_t)BB * HH); h0l[0] = alloc_us((size_t)BB * HH);
  h1h[0] = alloc_us((size_t)BB * HH); h1l[0] = alloc_us((size_t)BB * HH);
  float* c0 = alloc_f((size_t)BB * HH);
  float* c1 = alloc_f((size_t)BB * HH);
  h0h[1] = alloc_us((size_t)BB * HH); h0l[1] = alloc_us((size_t)BB * HH);
  h1h[1] = alloc_us((size_t)BB * HH); h1l[1] = alloc_us((size_t)BB * HH);
  u16* inph = alloc_us((size_t)BB * EPAD);
  u16* inpl = alloc_us((size_t)BB * EPAD);
  u16* Xench = alloc_us((size_t)TT * BB * EPAD);
  u16* Xencl = alloc_us((size_t)TT * BB * EPAD);
  u16* histh = alloc_us((size_t)PP * BB * HH);
  u16* histl = alloc_us((size_t)PP * BB * HH);

  // prep: 3 fused launches + memset
  {
    SJobs js = {{
      { e_Wih0, We0ih_h, We0ih_l, G4, EE, G4, EPAD },
      { e_Whh0, We0hh_h, We0hh_l, G4, HH, G4, HH },
      { e_Wih1, We1ih_h, We1ih_l, G4, HH, G4, HH },
      { e_Whh1, We1hh_h, We1hh_l, G4, HH, G4, HH },
      { d_Wih0, Wd0ih_h, Wd0ih_l, G4, EE, G4, EPAD },
      { d_Whh0, Wd0hh_h, Wd0hh_l, G4, HH, G4, HH },
      { d_Wih1, Wd1ih_h, Wd1ih_l, G4, HH, G4, HH },
      { d_Whh1, Wd1hh_h, Wd1hh_l, G4, HH, G4, HH },
      { fc_W,   Wfc_h,   Wfc_l,   CC, HH, NFC, HH },
    }};
    split_multi<<<1024, 256, 0, stream>>>(js);
  }
  wcomb_fused<<<G4, 256, 0, stream>>>(d_Wih0, fc_W, d_bih0, d_bhh0, fc_b, Wc_h, Wc_l, bd0c);
  prep_misc<<<2048, 256, 0, stream>>>(
      e_bih0, e_bhh0, be0, e_bih1, e_bhh1, be1,
      d_bih0, d_bhh0, bd0, d_bih1, d_bhh1, bd1,
      fc_b, bfc, x_enc, inph, inpl, Xench, Xencl);
  hipMemsetAsync(h0h[0], 0, (size_t)4 * BB * HH * sizeof(u16) + (size_t)2 * BB * HH * sizeof(float), stream);

  // encoder: fused pipeline, iteration t runs cell0(t) and cell1(t-1); M=64, 512 blocks, 2/CU
  for (int t = 0; t <= TT; ++t){
    const int rd = t & 1, wrp = (t + 1) & 1;
    const size_t ts = (size_t)(t < TT ? t : 0) * BB * EPAD;
    lstm_pair<<<512, 256, DEC_SMEM, stream>>>(
        (t < TT) ? 1 : 0, Xench + ts, Xencl + ts,
        We0ih_h, We0ih_l, We0hh_h, We0hh_l, be0,
        h0h[rd], h0l[rd], h0h[wrp], h0l[wrp], c0,
        (t > 0) ? 1 : 0, h0h[rd], h0l[rd],
        We1ih_h, We1ih_l, We1hh_h, We1hh_l, be1,
        h1h[wrp], h1l[wrp], h1h[rd], h1l[rd], c1);
  }
  // encoder finals land at parity 0 for both h0 and h1

  // decoder: split-overlap schedule (round-5 proven).
  // A(p)={fin0 (K=512/EPAD, +Gp0)} ∥ {part1: h1(p-1)@Wd1hh -> Gp1}
  // B(p)={fin1 (K=512, +Gp1), writes hist[p]} ∥ {part0: h0(p)@Wd0hh -> Gp0}
  const size_t S = (size_t)BB * HH;
  part_only<<<256, 256, DEC_SMEM, stream>>>(h0h[0], h0l[0], Wd0hh_h, Wd0hh_l, Gp0);
  for (int p = 0; p < PP; ++p){
    const u16* hp_h = p ? histh + (size_t)(p - 1) * S : h1h[0];
    const u16* hp_l = p ? histl + (size_t)(p - 1) * S : h1l[0];
    dec_ab<<<512, 256, DEC_SMEM, stream>>>(
        p ? hp_h : inph, p ? hp_l : inpl, p ? HH : EPAD,
        p ? Wc_h : Wd0ih_h, p ? Wc_l : Wd0ih_l,
        p ? bd0c : bd0, Gp0,
        h0h[1], h0l[1], c0,
        hp_h, hp_l, Wd1hh_h, Wd1hh_l, Gp1);
    dec_ab<<<512, 256, DEC_SMEM, stream>>>(
        h0h[1], h0l[1], HH,
        Wd1ih_h, Wd1ih_l,
        bd1, Gp1,
        histh + (size_t)p * S, histl + (size_t)p * S, c1,
        h0h[1], h0l[1], Wd0hh_h, Wd0hh_l, Gp0);
  }

  // batched FC over all 96 decoder steps
  fc_batch<<<dim3((PP * BB) / 128, NFC / 64), 256, FC_SMEM, stream>>>(
      histh, histl, Wfc_h, Wfc_l, bfc, (float*)d_out);
}